// Round 8
// baseline (746.811 us; speedup 1.0000x reference)
//
#include <hip/hip_runtime.h>
#include <hip/hip_fp16.h>
#include <math.h>

#define NN 20000
#define NE 320000
#define NT 16
#define NEG 0.2f
#define NCHUNK 16
#define CHSZ (NE / NCHUNK)   // 20000

__device__ __forceinline__ int d_src_of(int t) { return t < 4 ? t : (t - 4) / 3; }
__device__ __forceinline__ int d_dst_of(int t) {
    if (t < 4) return t;
    int i = t - 4, s = i / 3, j = i % 3;
    return j + (j >= s ? 1 : 0);
}

// ============ CSR 1: per-(type,chunk) histogram -> u16 packed counts ============
__global__ void hist2(const int* __restrict__ edges, unsigned short* __restrict__ counts16) {
    int t = blockIdx.x >> 4, chunk = blockIdx.x & 15;
    __shared__ unsigned h[NN / 2];  // 40 KB, two u16 bins per word
    for (int i = threadIdx.x; i < NN / 2; i += 256) h[i] = 0;
    __syncthreads();
    const int* dstp = edges + (size_t)t * 2 * NE + NE + chunk * CHSZ;
    for (int e = threadIdx.x; e < CHSZ; e += 256) {
        int d = dstp[e];
        atomicAdd(&h[d >> 1], (d & 1) ? 0x10000u : 1u);
    }
    __syncthreads();
    unsigned* cout = (unsigned*)(counts16 + ((size_t)t * NCHUNK + chunk) * NN);
    for (int i = threadIdx.x; i < NN / 2; i += 256) cout[i] = h[i];
}

// ============ CSR 2: totals + in-place exclusive prefix over chunks (packed) ============
__global__ void sumtot16(unsigned short* __restrict__ counts16, int* __restrict__ totals) {
    int idx = blockIdx.x * 256 + threadIdx.x;  // t*(NN/2) + i
    if (idx >= NT * NN / 2) return;
    int t = idx / (NN / 2), i = idx % (NN / 2);
    unsigned* base = (unsigned*)counts16 + (size_t)t * NCHUNK * (NN / 2) + i;
    unsigned run0 = 0, run1 = 0;
#pragma unroll
    for (int c = 0; c < NCHUNK; c++) {
        unsigned v = base[(size_t)c * (NN / 2)];
        base[(size_t)c * (NN / 2)] = run0 | (run1 << 16);
        run0 += v & 0xffffu;
        run1 += v >> 16;
    }
    totals[t * NN + 2 * i]     = (int)run0;
    totals[t * NN + 2 * i + 1] = (int)run1;
}

// ============ CSR 3: exclusive scan per type (1024 threads) ============
__global__ void scan_kernel(const int* __restrict__ totals, int* __restrict__ row_ptr) {
    int t = blockIdx.x, tid = threadIdx.x;
    __shared__ int buf[1024];
    int running = 0;
    for (int base = 0; base < NN; base += 1024) {
        int i = base + tid;
        int v = (i < NN) ? totals[t * NN + i] : 0;
        buf[tid] = v;
        __syncthreads();
        for (int off = 1; off < 1024; off <<= 1) {
            int x = (tid >= off) ? buf[tid - off] : 0;
            __syncthreads();
            buf[tid] += x;
            __syncthreads();
        }
        if (i < NN) row_ptr[t * (NN + 1) + i] = running + buf[tid] - v;
        int tot = buf[1023];
        __syncthreads();
        running += tot;
    }
    if (tid == 0) row_ptr[t * (NN + 1) + NN] = running;
}

// ============ CSR 4: placement; type->XCD affinity so CSR region stays in one L2 ============
__global__ void place2(const int* __restrict__ edges, const unsigned short* __restrict__ counts16,
                       const int* __restrict__ row_ptr, int* __restrict__ csr_src) {
    int t = blockIdx.x & 15, chunk = blockIdx.x >> 4;
    __shared__ unsigned cur[NN / 2];
    for (int i = threadIdx.x; i < NN / 2; i += 256) cur[i] = 0;
    __syncthreads();
    const int* srcp = edges + (size_t)t * 2 * NE + chunk * CHSZ;
    const int* dstp = srcp + NE;
    const unsigned short* cb = counts16 + ((size_t)t * NCHUNK + chunk) * NN;
    const int* rp = row_ptr + t * (NN + 1);
    int* cs = csr_src + (size_t)t * NE;
    for (int e = threadIdx.x; e < CHSZ; e += 256) {
        int d = dstp[e];
        unsigned old = atomicAdd(&cur[d >> 1], (d & 1) ? 0x10000u : 1u);
        int off = (d & 1) ? (int)(old >> 16) : (int)(old & 0xffffu);
        cs[rp[d] + (int)cb[d] + off] = srcp[e];
    }
}

// ============ precompute u = reduce(W * a) over c ============
__global__ void precompute_u(const float* __restrict__ W1, const float* __restrict__ as1,
                             const float* __restrict__ ad1, const float* __restrict__ W2,
                             const float* __restrict__ as2, const float* __restrict__ ad2,
                             float* __restrict__ u1s, float* __restrict__ u1d,
                             float* __restrict__ u2s, float* __restrict__ u2d) {
    int t = blockIdx.x, tid = threadIdx.x;  // 128 threads
    int k = tid >> 2, h = tid & 3;
    float ss = 0.f, dd = 0.f;
    for (int c = 0; c < 32; c++) {
        float w = W2[(size_t)t * 4096 + k * 128 + h * 32 + c];
        ss += w * as2[t * 128 + h * 32 + c];
        dd += w * ad2[t * 128 + h * 32 + c];
    }
    u2s[(t * 32 + k) * 4 + h] = ss;
    u2d[(t * 32 + k) * 4 + h] = dd;
    if (tid < 4) {
        int hh = tid;
        float s1 = 0.f, d1 = 0.f;
        for (int c = 0; c < 32; c++) {
            float w = W1[t * 128 + hh * 32 + c];
            s1 += w * as1[t * 128 + hh * 32 + c];
            d1 += w * ad1[t * 128 + hh * 32 + c];
        }
        u1s[t * 4 + hh] = s1;
        u1d[t * 4 + hh] = d1;
    }
}

// ============ Layer 1: fused attention + aggregation (no max-sub: |logit| < ~1) ============
__global__ void layer1_fused(const float* __restrict__ x, const int* __restrict__ csr_src,
                             const int* __restrict__ row_ptr, const float* __restrict__ u1s,
                             const float* __restrict__ u1d, float4* __restrict__ g1) {
    int t = blockIdx.y;
    int d = blockIdx.x * 256 + threadIdx.x;
    if (d >= NN) return;
    int sc = d_src_of(t), dc = d_dst_of(t);
    float xd = x[dc * NN + d];
    float4 usv = ((const float4*)u1s)[t];
    float4 udv = ((const float4*)u1d)[t];
    float us[4] = {usv.x, usv.y, usv.z, usv.w};
    float dl[4] = {xd * udv.x, xd * udv.y, xd * udv.z, xd * udv.w};
    int rb = row_ptr[t * (NN + 1) + d], re = row_ptr[t * (NN + 1) + d + 1];
    float dn[4] = {0, 0, 0, 0}, a[4] = {0, 0, 0, 0};
    const int* cs = csr_src + (size_t)t * NE;
#pragma unroll 2
    for (int i = rb; i < re; i++) {
        int s = __builtin_nontemporal_load(cs + i);  // read-once stream: keep out of L2
        float xs = x[sc * NN + s];
#pragma unroll
        for (int h = 0; h < 4; h++) {
            float l = xs * us[h] + dl[h];
            l = l > 0.f ? l : NEG * l;
            float p = __expf(l);
            dn[h] += p;
            a[h] += p * xs;
        }
    }
    float4 g;
    g.x = (re > rb) ? a[0] / dn[0] : 0.f;
    g.y = (re > rb) ? a[1] / dn[1] : 0.f;
    g.z = (re > rb) ? a[2] / dn[2] : 0.f;
    g.w = (re > rb) ? a[3] / dn[3] : 0.f;
    g1[t * NN + d] = g;
}

// ============ Layer 1 transform ============
__global__ void transform1(const float4* __restrict__ g1, const float* __restrict__ W1,
                           const float* __restrict__ b1, float* __restrict__ x1) {
    int idx = blockIdx.x * 256 + threadIdx.x;  // [ch][n][c]
    if (idx >= 4 * NN * 32) return;
    int c = idx & 31;
    int n = (idx >> 5) % NN;
    int ch = idx / (NN * 32);
    float sum = 0.f, bs = 0.f;
#pragma unroll
    for (int t = 0; t < NT; t++) {
        if (d_dst_of(t) == ch) {
            float4 g = g1[t * NN + n];
            const float* w = W1 + t * 128 + c;
            sum += 0.25f * (g.x * w[0] + g.y * w[32] + g.z * w[64] + g.w * w[96]);
            bs += b1[t * 32 + c];
        }
    }
    float v = 0.25f * (sum + bs);
    x1[idx] = v > 0.f ? v : 0.f;
}

// ============ Layer 2 scores (float4 k-loop) ============
__global__ void scores2(const float* __restrict__ x1, const float* __restrict__ u2s,
                        const float* __restrict__ u2d, float4* __restrict__ ss,
                        float4* __restrict__ ds) {
    int t = blockIdx.y;
    int n = blockIdx.x * 256 + threadIdx.x;
    if (n >= NN) return;
    int sc = d_src_of(t), dc = d_dst_of(t);
    const float4* xsr = (const float4*)(x1 + ((size_t)sc * NN + n) * 32);
    const float4* xdr = (const float4*)(x1 + ((size_t)dc * NN + n) * 32);
    const float4* us = (const float4*)(u2s + (size_t)t * 128);  // row k = float4 over h
    const float4* ud = (const float4*)(u2d + (size_t)t * 128);
    float4 s4 = make_float4(0.f, 0.f, 0.f, 0.f);
    float4 d4 = make_float4(0.f, 0.f, 0.f, 0.f);
#pragma unroll
    for (int kq = 0; kq < 8; kq++) {
        float4 xs = xsr[kq], xd = xdr[kq];
#pragma unroll
        for (int m = 0; m < 4; m++) {
            float xsk = (&xs.x)[m], xdk = (&xd.x)[m];
            float4 u = us[4 * kq + m], v = ud[4 * kq + m];
            s4.x += xsk * u.x; s4.y += xsk * u.y; s4.z += xsk * u.z; s4.w += xsk * u.w;
            d4.x += xdk * v.x; d4.y += xdk * v.y; d4.z += xdk * v.z; d4.w += xdk * v.w;
        }
    }
    ss[t * NN + n] = s4;
    ds[t * NN + n] = d4;
}

// ============ Layer 2a: SINGLE-PASS unnormalized exp (half4) + per-dst denom ============
__global__ void alpha2s(const int* __restrict__ csr_src, const int* __restrict__ row_ptr,
                        const float4* __restrict__ ss, const float4* __restrict__ ds,
                        unsigned long long* __restrict__ alpha, float4* __restrict__ dn2) {
    int t = blockIdx.y;
    int d = blockIdx.x * 256 + threadIdx.x;
    if (d >= NN) return;
    float4 dsv = ds[t * NN + d];
    float dl[4] = {dsv.x, dsv.y, dsv.z, dsv.w};
    int rb = row_ptr[t * (NN + 1) + d], re = row_ptr[t * (NN + 1) + d + 1];
    const int* cs = csr_src + (size_t)t * NE;
    unsigned long long* ap = alpha + (size_t)t * NE;
    float dn[4] = {0, 0, 0, 0};
#pragma unroll 2
    for (int i = rb; i < re; i++) {
        int s = __builtin_nontemporal_load(cs + i);
        float4 sv = ss[t * NN + s];
        float p0, p1, p2, p3;
        { float l = sv.x + dl[0]; l = l > 0.f ? l : NEG * l; p0 = __expf(l); }
        { float l = sv.y + dl[1]; l = l > 0.f ? l : NEG * l; p1 = __expf(l); }
        { float l = sv.z + dl[2]; l = l > 0.f ? l : NEG * l; p2 = __expf(l); }
        { float l = sv.w + dl[3]; l = l > 0.f ? l : NEG * l; p3 = __expf(l); }
        dn[0] += p0; dn[1] += p1; dn[2] += p2; dn[3] += p3;
        __half2 h01 = __floats2half2_rn(p0, p1);
        __half2 h23 = __floats2half2_rn(p2, p3);
        unsigned long long q = (unsigned long long)(*(unsigned*)&h01) |
                               ((unsigned long long)(*(unsigned*)&h23) << 32);
        __builtin_nontemporal_store(q, ap + i);  // read-once stream
    }
    dn2[t * NN + d] = make_float4(dn[0], dn[1], dn[2], dn[3]);
}

// ============ Layer 2b: gather+FMA aggregation + denom + W2 + bias + means + relu ============
// 1D grid 10000; channel->XCD affinity: xcd = b&7, ch = xcd>>1 so each XCD's L2 holds
// only ONE 2.56MB x1 source table per phase (was 4 tables + streams -> thrash).
// NOTE: phase loop MUST NOT be unrolled — unrolling merges 4 phases' staging loads and
// blows past 256 VGPRs into scratch spills (round-4 regression: 2.9 GB scratch writes).
__global__ __launch_bounds__(256) void layer2_full(
    const float* __restrict__ x1, const int* __restrict__ csr_src,
    const int* __restrict__ row_ptr, const unsigned long long* __restrict__ alpha,
    const float4* __restrict__ dn2, const float* __restrict__ W2,
    const float* __restrict__ b2, float* __restrict__ out) {
    int b = blockIdx.x;
    int xcd = b & 7;
    int ch = xcd >> 1;
    int dt = (b >> 3) * 2 + (xcd & 1);   // 0..2499, each (ch,dt) exactly once
    int grp = threadIdx.x >> 5, lane = threadIdx.x & 31;
    int d = dt * 8 + grp;
    __shared__ float4 W2s[1024];     // 16 KB
    __shared__ float gl[8 * 128];    // 4 KB  -> 20 KB total
    const float* W2f = (const float*)W2s;
    float o = 0.f, bsum = 0.f;
#pragma unroll 1
    for (int j = 0; j < 4; j++) {
        int t, sc;
        if (j == 0) { t = ch; sc = ch; }
        else {
            int s = (j - 1) + ((j - 1) >= ch ? 1 : 0);        // enumerate s != ch
            t = 4 + s * 3 + (ch > s ? ch - 1 : ch);
            sc = s;
        }
        __syncthreads();  // protect W2s/gl from previous phase readers
        const float4* wsrc = (const float4*)(W2 + (size_t)t * 4096);
#pragma unroll
        for (int i = 0; i < 4; i++) W2s[threadIdx.x + i * 256] = wsrc[threadIdx.x + i * 256];
        bsum += b2[t * 32 + lane];
        int rb = row_ptr[t * (NN + 1) + d], re = row_ptr[t * (NN + 1) + d + 1];
        float val[4] = {0, 0, 0, 0};
        const int* cs = csr_src + (size_t)t * NE;
        const unsigned long long* ap = alpha + (size_t)t * NE;
        const float* xb = x1 + (size_t)sc * NN * 32;
        int i = rb;
        for (; i + 4 <= re; i += 4) {  // 4 independent gather chains in flight
            int s0 = __builtin_nontemporal_load(cs + i);
            int s1 = __builtin_nontemporal_load(cs + i + 1);
            int s2 = __builtin_nontemporal_load(cs + i + 2);
            int s3 = __builtin_nontemporal_load(cs + i + 3);
            unsigned long long a0 = __builtin_nontemporal_load(ap + i);
            unsigned long long a1 = __builtin_nontemporal_load(ap + i + 1);
            unsigned long long a2 = __builtin_nontemporal_load(ap + i + 2);
            unsigned long long a3 = __builtin_nontemporal_load(ap + i + 3);
            float x0 = xb[s0 * 32 + lane];
            float x1v = xb[s1 * 32 + lane];
            float x2 = xb[s2 * 32 + lane];
            float x3 = xb[s3 * 32 + lane];
            unsigned lo, hi;
            float2 p01, p23;
            lo = (unsigned)a0; hi = (unsigned)(a0 >> 32);
            p01 = __half22float2(*(const __half2*)&lo); p23 = __half22float2(*(const __half2*)&hi);
            val[0] += p01.x * x0; val[1] += p01.y * x0; val[2] += p23.x * x0; val[3] += p23.y * x0;
            lo = (unsigned)a1; hi = (unsigned)(a1 >> 32);
            p01 = __half22float2(*(const __half2*)&lo); p23 = __half22float2(*(const __half2*)&hi);
            val[0] += p01.x * x1v; val[1] += p01.y * x1v; val[2] += p23.x * x1v; val[3] += p23.y * x1v;
            lo = (unsigned)a2; hi = (unsigned)(a2 >> 32);
            p01 = __half22float2(*(const __half2*)&lo); p23 = __half22float2(*(const __half2*)&hi);
            val[0] += p01.x * x2; val[1] += p01.y * x2; val[2] += p23.x * x2; val[3] += p23.y * x2;
            lo = (unsigned)a3; hi = (unsigned)(a3 >> 32);
            p01 = __half22float2(*(const __half2*)&lo); p23 = __half22float2(*(const __half2*)&hi);
            val[0] += p01.x * x3; val[1] += p01.y * x3; val[2] += p23.x * x3; val[3] += p23.y * x3;
        }
        for (; i < re; i++) {
            int s = __builtin_nontemporal_load(cs + i);
            unsigned long long a = __builtin_nontemporal_load(ap + i);
            float xk = xb[s * 32 + lane];
            unsigned lo = (unsigned)a, hi = (unsigned)(a >> 32);
            float2 p01 = __half22float2(*(const __half2*)&lo);
            float2 p23 = __half22float2(*(const __half2*)&hi);
            val[0] += p01.x * xk; val[1] += p01.y * xk; val[2] += p23.x * xk; val[3] += p23.y * xk;
        }
        float4 dnv = dn2[t * NN + d];
        float r0 = dnv.x > 0.f ? 1.f / dnv.x : 0.f;
        float r1 = dnv.y > 0.f ? 1.f / dnv.y : 0.f;
        float r2 = dnv.z > 0.f ? 1.f / dnv.z : 0.f;
        float r3 = dnv.w > 0.f ? 1.f / dnv.w : 0.f;
        gl[grp * 128 +       lane] = val[0] * r0;
        gl[grp * 128 +  32 + lane] = val[1] * r1;
        gl[grp * 128 +  64 + lane] = val[2] * r2;
        gl[grp * 128 +  96 + lane] = val[3] * r3;
        __syncthreads();
        float acc = 0.f;
#pragma unroll 4
        for (int k = 0; k < 32; k++) {
            const float* gb = gl + grp * 128 + k;
            const float* wb = W2f + k * 128 + lane;
            acc += gb[0] * wb[0] + gb[32] * wb[32] + gb[64] * wb[64] + gb[96] * wb[96];
        }
        o += acc;
    }
    float r = o * 0.0625f + bsum * 0.25f;  // (/H=4 then /4 types) ; (bias sum)/4
    r = r > 0.f ? r : 0.f;
    out[(size_t)d * 128 + ch * 32 + lane] = r;
}

extern "C" void kernel_launch(void* const* d_in, const int* in_sizes, int n_in,
                              void* d_out, int out_size, void* d_ws, size_t ws_size,
                              hipStream_t stream) {
    const float* x   = (const float*)d_in[0];
    const int*   edg = (const int*)d_in[1];
    const float* W1  = (const float*)d_in[2];
    const float* as1 = (const float*)d_in[3];
    const float* ad1 = (const float*)d_in[4];
    const float* b1  = (const float*)d_in[5];
    const float* W2  = (const float*)d_in[6];
    const float* as2 = (const float*)d_in[7];
    const float* ad2 = (const float*)d_in[8];
    const float* b2  = (const float*)d_in[9];
    float* out = (float*)d_out;

    char* w = (char*)d_ws;
    auto carve = [&](size_t bytes) {
        void* p = (void*)w;
        w += (bytes + 255) & ~(size_t)255;
        return p;
    };
    int*   csr_src = (int*)carve((size_t)NT * NE * 4);        // 20.5 MB
    int*   row_ptr = (int*)carve((size_t)NT * (NN + 1) * 4);  // 1.3 MB
    float* u1s     = (float*)carve(NT * 4 * 4);
    float* u1d     = (float*)carve(NT * 4 * 4);
    float* u2s     = (float*)carve(NT * 32 * 4 * 4);
    float* u2d     = (float*)carve(NT * 32 * 4 * 4);
    float* x1      = (float*)carve((size_t)4 * NN * 32 * 4);  // 10.2 MB
    float* ss      = (float*)carve((size_t)NT * NN * 4 * 4);  // 5.1 MB
    float* ds      = (float*)carve((size_t)NT * NN * 4 * 4);  // 5.1 MB
    float4* dn2    = (float4*)carve((size_t)NT * NN * 16);    // 5.1 MB
    // time-multiplexed region (41 MB): {counts16+totals} -> {g1} -> {alpha}
    char* region   = (char*)carve((size_t)NT * NE * 8);
    unsigned short* counts16 = (unsigned short*)region;                       // 10.2 MB
    int*            totals   = (int*)(region + (size_t)NT * NCHUNK * NN * 2); // 1.3 MB
    float4*         g1       = (float4*)region;                               // 5.1 MB
    unsigned long long* alpha = (unsigned long long*)region;                  // 41 MB

    // ---- CSR build ----
    hist2<<<NT * NCHUNK, 256, 0, stream>>>(edg, counts16);
    sumtot16<<<(NT * NN / 2 + 255) / 256, 256, 0, stream>>>(counts16, totals);
    scan_kernel<<<NT, 1024, 0, stream>>>(totals, row_ptr);
    place2<<<NT * NCHUNK, 256, 0, stream>>>(edg, counts16, row_ptr, csr_src);
    precompute_u<<<NT, 128, 0, stream>>>(W1, as1, ad1, W2, as2, ad2, u1s, u1d, u2s, u2d);

    // ---- Layer 1 ----
    dim3 gtn((NN + 255) / 256, NT);
    layer1_fused<<<gtn, 256, 0, stream>>>(x, csr_src, row_ptr, u1s, u1d, g1);
    transform1<<<(4 * NN * 32 + 255) / 256, 256, 0, stream>>>(g1, W1, b1, x1);

    // ---- Layer 2 ----
    scores2<<<gtn, 256, 0, stream>>>(x1, u2s, u2d, (float4*)ss, (float4*)ds);
    alpha2s<<<gtn, 256, 0, stream>>>(csr_src, row_ptr, (const float4*)ss, (const float4*)ds,
                                     alpha, dn2);
    layer2_full<<<10000, 256, 0, stream>>>(x1, csr_src, row_ptr, alpha, dn2, W2, b2, out);
}

// Round 9
// 716.452 us; speedup vs baseline: 1.0424x; 1.0424x over previous
//
#include <hip/hip_runtime.h>
#include <hip/hip_fp16.h>
#include <math.h>

#define NN 20000
#define NE 320000
#define NT 16
#define NEG 0.2f
#define NCHUNK 16
#define CHSZ (NE / NCHUNK)   // 20000

__device__ __forceinline__ int d_src_of(int t) { return t < 4 ? t : (t - 4) / 3; }
__device__ __forceinline__ int d_dst_of(int t) {
    if (t < 4) return t;
    int i = t - 4, s = i / 3, j = i % 3;
    return j + (j >= s ? 1 : 0);
}

// ============ CSR 1: per-(type,chunk) histogram -> u16 packed counts ============
__global__ void hist2(const int* __restrict__ edges, unsigned short* __restrict__ counts16) {
    int t = blockIdx.x >> 4, chunk = blockIdx.x & 15;
    __shared__ unsigned h[NN / 2];  // 40 KB, two u16 bins per word
    for (int i = threadIdx.x; i < NN / 2; i += 256) h[i] = 0;
    __syncthreads();
    const int* dstp = edges + (size_t)t * 2 * NE + NE + chunk * CHSZ;
    for (int e = threadIdx.x; e < CHSZ; e += 256) {
        int d = dstp[e];
        atomicAdd(&h[d >> 1], (d & 1) ? 0x10000u : 1u);
    }
    __syncthreads();
    unsigned* cout = (unsigned*)(counts16 + ((size_t)t * NCHUNK + chunk) * NN);
    for (int i = threadIdx.x; i < NN / 2; i += 256) cout[i] = h[i];
}

// ============ CSR 2: totals + in-place exclusive prefix over chunks (packed) ============
__global__ void sumtot16(unsigned short* __restrict__ counts16, int* __restrict__ totals) {
    int idx = blockIdx.x * 256 + threadIdx.x;  // t*(NN/2) + i
    if (idx >= NT * NN / 2) return;
    int t = idx / (NN / 2), i = idx % (NN / 2);
    unsigned* base = (unsigned*)counts16 + (size_t)t * NCHUNK * (NN / 2) + i;
    unsigned run0 = 0, run1 = 0;
#pragma unroll
    for (int c = 0; c < NCHUNK; c++) {
        unsigned v = base[(size_t)c * (NN / 2)];
        base[(size_t)c * (NN / 2)] = run0 | (run1 << 16);
        run0 += v & 0xffffu;
        run1 += v >> 16;
    }
    totals[t * NN + 2 * i]     = (int)run0;
    totals[t * NN + 2 * i + 1] = (int)run1;
}

// ============ CSR 3: exclusive scan per type (1024 threads) ============
__global__ void scan_kernel(const int* __restrict__ totals, int* __restrict__ row_ptr) {
    int t = blockIdx.x, tid = threadIdx.x;
    __shared__ int buf[1024];
    int running = 0;
    for (int base = 0; base < NN; base += 1024) {
        int i = base + tid;
        int v = (i < NN) ? totals[t * NN + i] : 0;
        buf[tid] = v;
        __syncthreads();
        for (int off = 1; off < 1024; off <<= 1) {
            int x = (tid >= off) ? buf[tid - off] : 0;
            __syncthreads();
            buf[tid] += x;
            __syncthreads();
        }
        if (i < NN) row_ptr[t * (NN + 1) + i] = running + buf[tid] - v;
        int tot = buf[1023];
        __syncthreads();
        running += tot;
    }
    if (tid == 0) row_ptr[t * (NN + 1) + NN] = running;
}

// ============ CSR 4: placement; type->XCD affinity so CSR region stays in one L2 ============
__global__ void place2(const int* __restrict__ edges, const unsigned short* __restrict__ counts16,
                       const int* __restrict__ row_ptr, int* __restrict__ csr_src) {
    int t = blockIdx.x & 15, chunk = blockIdx.x >> 4;
    __shared__ unsigned cur[NN / 2];
    for (int i = threadIdx.x; i < NN / 2; i += 256) cur[i] = 0;
    __syncthreads();
    const int* srcp = edges + (size_t)t * 2 * NE + chunk * CHSZ;
    const int* dstp = srcp + NE;
    const unsigned short* cb = counts16 + ((size_t)t * NCHUNK + chunk) * NN;
    const int* rp = row_ptr + t * (NN + 1);
    int* cs = csr_src + (size_t)t * NE;
    for (int e = threadIdx.x; e < CHSZ; e += 256) {
        int d = dstp[e];
        unsigned old = atomicAdd(&cur[d >> 1], (d & 1) ? 0x10000u : 1u);
        int off = (d & 1) ? (int)(old >> 16) : (int)(old & 0xffffu);
        cs[rp[d] + (int)cb[d] + off] = srcp[e];
    }
}

// ============ precompute u = reduce(W * a) over c ============
__global__ void precompute_u(const float* __restrict__ W1, const float* __restrict__ as1,
                             const float* __restrict__ ad1, const float* __restrict__ W2,
                             const float* __restrict__ as2, const float* __restrict__ ad2,
                             float* __restrict__ u1s, float* __restrict__ u1d,
                             float* __restrict__ u2s, float* __restrict__ u2d) {
    int t = blockIdx.x, tid = threadIdx.x;  // 128 threads
    int k = tid >> 2, h = tid & 3;
    float ss = 0.f, dd = 0.f;
    for (int c = 0; c < 32; c++) {
        float w = W2[(size_t)t * 4096 + k * 128 + h * 32 + c];
        ss += w * as2[t * 128 + h * 32 + c];
        dd += w * ad2[t * 128 + h * 32 + c];
    }
    u2s[(t * 32 + k) * 4 + h] = ss;
    u2d[(t * 32 + k) * 4 + h] = dd;
    if (tid < 4) {
        int hh = tid;
        float s1 = 0.f, d1 = 0.f;
        for (int c = 0; c < 32; c++) {
            float w = W1[t * 128 + hh * 32 + c];
            s1 += w * as1[t * 128 + hh * 32 + c];
            d1 += w * ad1[t * 128 + hh * 32 + c];
        }
        u1s[t * 4 + hh] = s1;
        u1d[t * 4 + hh] = d1;
    }
}

// ============ Layer 1: fused attention + aggregation (no max-sub: |logit| < ~1) ============
__global__ void layer1_fused(const float* __restrict__ x, const int* __restrict__ csr_src,
                             const int* __restrict__ row_ptr, const float* __restrict__ u1s,
                             const float* __restrict__ u1d, float4* __restrict__ g1) {
    int t = blockIdx.y;
    int d = blockIdx.x * 256 + threadIdx.x;
    if (d >= NN) return;
    int sc = d_src_of(t), dc = d_dst_of(t);
    float xd = x[dc * NN + d];
    float4 usv = ((const float4*)u1s)[t];
    float4 udv = ((const float4*)u1d)[t];
    float us[4] = {usv.x, usv.y, usv.z, usv.w};
    float dl[4] = {xd * udv.x, xd * udv.y, xd * udv.z, xd * udv.w};
    int rb = row_ptr[t * (NN + 1) + d], re = row_ptr[t * (NN + 1) + d + 1];
    float dn[4] = {0, 0, 0, 0}, a[4] = {0, 0, 0, 0};
    const int* cs = csr_src + (size_t)t * NE;
#pragma unroll 2
    for (int i = rb; i < re; i++) {
        int s = cs[i];
        float xs = x[sc * NN + s];
#pragma unroll
        for (int h = 0; h < 4; h++) {
            float l = xs * us[h] + dl[h];
            l = l > 0.f ? l : NEG * l;
            float p = __expf(l);
            dn[h] += p;
            a[h] += p * xs;
        }
    }
    float4 g;
    g.x = (re > rb) ? a[0] / dn[0] : 0.f;
    g.y = (re > rb) ? a[1] / dn[1] : 0.f;
    g.z = (re > rb) ? a[2] / dn[2] : 0.f;
    g.w = (re > rb) ? a[3] / dn[3] : 0.f;
    g1[t * NN + d] = g;
}

// ============ Layer 1 transform ============
__global__ void transform1(const float4* __restrict__ g1, const float* __restrict__ W1,
                           const float* __restrict__ b1, float* __restrict__ x1) {
    int idx = blockIdx.x * 256 + threadIdx.x;  // [ch][n][c]
    if (idx >= 4 * NN * 32) return;
    int c = idx & 31;
    int n = (idx >> 5) % NN;
    int ch = idx / (NN * 32);
    float sum = 0.f, bs = 0.f;
#pragma unroll
    for (int t = 0; t < NT; t++) {
        if (d_dst_of(t) == ch) {
            float4 g = g1[t * NN + n];
            const float* w = W1 + t * 128 + c;
            sum += 0.25f * (g.x * w[0] + g.y * w[32] + g.z * w[64] + g.w * w[96]);
            bs += b1[t * 32 + c];
        }
    }
    float v = 0.25f * (sum + bs);
    x1[idx] = v > 0.f ? v : 0.f;
}

// ============ Layer 2 scores (float4 k-loop) ============
__global__ void scores2(const float* __restrict__ x1, const float* __restrict__ u2s,
                        const float* __restrict__ u2d, float4* __restrict__ ss,
                        float4* __restrict__ ds) {
    int t = blockIdx.y;
    int n = blockIdx.x * 256 + threadIdx.x;
    if (n >= NN) return;
    int sc = d_src_of(t), dc = d_dst_of(t);
    const float4* xsr = (const float4*)(x1 + ((size_t)sc * NN + n) * 32);
    const float4* xdr = (const float4*)(x1 + ((size_t)dc * NN + n) * 32);
    const float4* us = (const float4*)(u2s + (size_t)t * 128);  // row k = float4 over h
    const float4* ud = (const float4*)(u2d + (size_t)t * 128);
    float4 s4 = make_float4(0.f, 0.f, 0.f, 0.f);
    float4 d4 = make_float4(0.f, 0.f, 0.f, 0.f);
#pragma unroll
    for (int kq = 0; kq < 8; kq++) {
        float4 xs = xsr[kq], xd = xdr[kq];
#pragma unroll
        for (int m = 0; m < 4; m++) {
            float xsk = (&xs.x)[m], xdk = (&xd.x)[m];
            float4 u = us[4 * kq + m], v = ud[4 * kq + m];
            s4.x += xsk * u.x; s4.y += xsk * u.y; s4.z += xsk * u.z; s4.w += xsk * u.w;
            d4.x += xdk * v.x; d4.y += xdk * v.y; d4.z += xdk * v.z; d4.w += xdk * v.w;
        }
    }
    ss[t * NN + n] = s4;
    ds[t * NN + n] = d4;
}

// ============ Layer 2a: SINGLE-PASS unnormalized exp (half4) + per-dst denom ============
// normal stores — alpha must stay L2-resident for layer2_full (round-8 lesson: nt
// stores here forced +65MB of HBM round-trips)
__global__ void alpha2s(const int* __restrict__ csr_src, const int* __restrict__ row_ptr,
                        const float4* __restrict__ ss, const float4* __restrict__ ds,
                        unsigned long long* __restrict__ alpha, float4* __restrict__ dn2) {
    int t = blockIdx.y;
    int d = blockIdx.x * 256 + threadIdx.x;
    if (d >= NN) return;
    float4 dsv = ds[t * NN + d];
    float dl[4] = {dsv.x, dsv.y, dsv.z, dsv.w};
    int rb = row_ptr[t * (NN + 1) + d], re = row_ptr[t * (NN + 1) + d + 1];
    const int* cs = csr_src + (size_t)t * NE;
    unsigned long long* ap = alpha + (size_t)t * NE;
    float dn[4] = {0, 0, 0, 0};
#pragma unroll 2
    for (int i = rb; i < re; i++) {
        int s = cs[i];
        float4 sv = ss[t * NN + s];
        float p0, p1, p2, p3;
        { float l = sv.x + dl[0]; l = l > 0.f ? l : NEG * l; p0 = __expf(l); }
        { float l = sv.y + dl[1]; l = l > 0.f ? l : NEG * l; p1 = __expf(l); }
        { float l = sv.z + dl[2]; l = l > 0.f ? l : NEG * l; p2 = __expf(l); }
        { float l = sv.w + dl[3]; l = l > 0.f ? l : NEG * l; p3 = __expf(l); }
        dn[0] += p0; dn[1] += p1; dn[2] += p2; dn[3] += p3;
        __half2 h01 = __floats2half2_rn(p0, p1);
        __half2 h23 = __floats2half2_rn(p2, p3);
        ap[i] = (unsigned long long)(*(unsigned*)&h01) |
                ((unsigned long long)(*(unsigned*)&h23) << 32);
    }
    dn2[t * NN + d] = make_float4(dn[0], dn[1], dn[2], dn[3]);
}

// ============ Layer 2b: gather+FMA aggregation + denom + W2 + bias + means + relu ============
// grid (NN/8, 4 channels); group of 32 lanes owns one dst node, loops its 4 incoming types.
// nt loads ONLY here (last reader of cs/alpha): streams don't evict the hot x1 tables,
// but still hit L2-dirty lines written by place2/alpha2s.
// Epilogue: W2 staged TRANSPOSED (W2t[k][c][h]) + gl as float4-over-h so the k-loop is
// 2x ds_read_b128 + 4 FMA (was 8 scalar LDS + 4 FMA).
// NOTE: phase loop MUST NOT be unrolled — unrolling merges 4 phases' staging loads and
// blows past 256 VGPRs into scratch spills (round-4 regression: 2.9 GB scratch writes).
__global__ __launch_bounds__(256) void layer2_full(
    const float* __restrict__ x1, const int* __restrict__ csr_src,
    const int* __restrict__ row_ptr, const unsigned long long* __restrict__ alpha,
    const float4* __restrict__ dn2, const float* __restrict__ W2,
    const float* __restrict__ b2, float* __restrict__ out) {
    int ch = blockIdx.y;
    int grp = threadIdx.x >> 5, lane = threadIdx.x & 31;
    int d = blockIdx.x * 8 + grp;    // grid.x = 2500, exact
    __shared__ float W2t[4096];      // 16 KB, [k][c][h]
    __shared__ float4 gl4[256];      // 4 KB, [grp][k] -> float4 over h
    const float4* W2t4 = (const float4*)W2t;
    float o = 0.f, bsum = 0.f;
#pragma unroll 1
    for (int j = 0; j < 4; j++) {
        int t, sc;
        if (j == 0) { t = ch; sc = ch; }
        else {
            int s = (j - 1) + ((j - 1) >= ch ? 1 : 0);        // enumerate s != ch
            t = 4 + s * 3 + (ch > s ? ch - 1 : ch);
            sc = s;
        }
        __syncthreads();  // protect W2t/gl4 from previous phase readers
        const float4* wsrc = (const float4*)(W2 + (size_t)t * 4096);
#pragma unroll
        for (int i0 = 0; i0 < 4; i0++) {
            int i = threadIdx.x + i0 * 256;      // i = k*32 + h*8 + cq
            float4 wv = wsrc[i];
            int k = i >> 5, h = (i >> 3) & 3, cq = i & 7;
            float* dst = W2t + k * 128 + cq * 16 + h;  // (k*32 + c)*4 + h, c=cq*4+m
            dst[0] = wv.x; dst[4] = wv.y; dst[8] = wv.z; dst[12] = wv.w;
        }
        bsum += b2[t * 32 + lane];
        int rb = row_ptr[t * (NN + 1) + d], re = row_ptr[t * (NN + 1) + d + 1];
        float val[4] = {0, 0, 0, 0};
        const int* cs = csr_src + (size_t)t * NE;
        const unsigned long long* ap = alpha + (size_t)t * NE;
        const float* xb = x1 + (size_t)sc * NN * 32;
        int i = rb;
        for (; i + 4 <= re; i += 4) {  // 4 independent gather chains in flight
            int s0 = __builtin_nontemporal_load(cs + i);
            int s1 = __builtin_nontemporal_load(cs + i + 1);
            int s2 = __builtin_nontemporal_load(cs + i + 2);
            int s3 = __builtin_nontemporal_load(cs + i + 3);
            unsigned long long a0 = __builtin_nontemporal_load(ap + i);
            unsigned long long a1 = __builtin_nontemporal_load(ap + i + 1);
            unsigned long long a2 = __builtin_nontemporal_load(ap + i + 2);
            unsigned long long a3 = __builtin_nontemporal_load(ap + i + 3);
            float x0 = xb[s0 * 32 + lane];
            float x1v = xb[s1 * 32 + lane];
            float x2 = xb[s2 * 32 + lane];
            float x3 = xb[s3 * 32 + lane];
            unsigned lo, hi;
            float2 p01, p23;
            lo = (unsigned)a0; hi = (unsigned)(a0 >> 32);
            p01 = __half22float2(*(const __half2*)&lo); p23 = __half22float2(*(const __half2*)&hi);
            val[0] += p01.x * x0; val[1] += p01.y * x0; val[2] += p23.x * x0; val[3] += p23.y * x0;
            lo = (unsigned)a1; hi = (unsigned)(a1 >> 32);
            p01 = __half22float2(*(const __half2*)&lo); p23 = __half22float2(*(const __half2*)&hi);
            val[0] += p01.x * x1v; val[1] += p01.y * x1v; val[2] += p23.x * x1v; val[3] += p23.y * x1v;
            lo = (unsigned)a2; hi = (unsigned)(a2 >> 32);
            p01 = __half22float2(*(const __half2*)&lo); p23 = __half22float2(*(const __half2*)&hi);
            val[0] += p01.x * x2; val[1] += p01.y * x2; val[2] += p23.x * x2; val[3] += p23.y * x2;
            lo = (unsigned)a3; hi = (unsigned)(a3 >> 32);
            p01 = __half22float2(*(const __half2*)&lo); p23 = __half22float2(*(const __half2*)&hi);
            val[0] += p01.x * x3; val[1] += p01.y * x3; val[2] += p23.x * x3; val[3] += p23.y * x3;
        }
        for (; i < re; i++) {
            int s = __builtin_nontemporal_load(cs + i);
            unsigned long long a = __builtin_nontemporal_load(ap + i);
            float xk = xb[s * 32 + lane];
            unsigned lo = (unsigned)a, hi = (unsigned)(a >> 32);
            float2 p01 = __half22float2(*(const __half2*)&lo);
            float2 p23 = __half22float2(*(const __half2*)&hi);
            val[0] += p01.x * xk; val[1] += p01.y * xk; val[2] += p23.x * xk; val[3] += p23.y * xk;
        }
        float4 dnv = dn2[t * NN + d];
        float r0 = dnv.x > 0.f ? 1.f / dnv.x : 0.f;
        float r1 = dnv.y > 0.f ? 1.f / dnv.y : 0.f;
        float r2 = dnv.z > 0.f ? 1.f / dnv.z : 0.f;
        float r3 = dnv.w > 0.f ? 1.f / dnv.w : 0.f;
        gl4[grp * 32 + lane] = make_float4(val[0] * r0, val[1] * r1, val[2] * r2, val[3] * r3);
        __syncthreads();
        float acc = 0.f;
#pragma unroll 8
        for (int k = 0; k < 32; k++) {
            float4 g4 = gl4[grp * 32 + k];       // LDS broadcast (b128)
            float4 w4 = W2t4[k * 32 + lane];     // consecutive b128, 2-way (free)
            acc += g4.x * w4.x + g4.y * w4.y + g4.z * w4.z + g4.w * w4.w;
        }
        o += acc;
    }
    float r = o * 0.0625f + bsum * 0.25f;  // (/H=4 then /4 types) ; (bias sum)/4
    r = r > 0.f ? r : 0.f;
    out[(size_t)d * 128 + ch * 32 + lane] = r;
}

extern "C" void kernel_launch(void* const* d_in, const int* in_sizes, int n_in,
                              void* d_out, int out_size, void* d_ws, size_t ws_size,
                              hipStream_t stream) {
    const float* x   = (const float*)d_in[0];
    const int*   edg = (const int*)d_in[1];
    const float* W1  = (const float*)d_in[2];
    const float* as1 = (const float*)d_in[3];
    const float* ad1 = (const float*)d_in[4];
    const float* b1  = (const float*)d_in[5];
    const float* W2  = (const float*)d_in[6];
    const float* as2 = (const float*)d_in[7];
    const float* ad2 = (const float*)d_in[8];
    const float* b2  = (const float*)d_in[9];
    float* out = (float*)d_out;

    char* w = (char*)d_ws;
    auto carve = [&](size_t bytes) {
        void* p = (void*)w;
        w += (bytes + 255) & ~(size_t)255;
        return p;
    };
    int*   csr_src = (int*)carve((size_t)NT * NE * 4);        // 20.5 MB
    int*   row_ptr = (int*)carve((size_t)NT * (NN + 1) * 4);  // 1.3 MB
    float* u1s     = (float*)carve(NT * 4 * 4);
    float* u1d     = (float*)carve(NT * 4 * 4);
    float* u2s     = (float*)carve(NT * 32 * 4 * 4);
    float* u2d     = (float*)carve(NT * 32 * 4 * 4);
    float* x1      = (float*)carve((size_t)4 * NN * 32 * 4);  // 10.2 MB
    float* ss      = (float*)carve((size_t)NT * NN * 4 * 4);  // 5.1 MB
    float* ds      = (float*)carve((size_t)NT * NN * 4 * 4);  // 5.1 MB
    float4* dn2    = (float4*)carve((size_t)NT * NN * 16);    // 5.1 MB
    // time-multiplexed region (41 MB): {counts16+totals} -> {g1} -> {alpha}
    char* region   = (char*)carve((size_t)NT * NE * 8);
    unsigned short* counts16 = (unsigned short*)region;                       // 10.2 MB
    int*            totals   = (int*)(region + (size_t)NT * NCHUNK * NN * 2); // 1.3 MB
    float4*         g1       = (float4*)region;                               // 5.1 MB
    unsigned long long* alpha = (unsigned long long*)region;                  // 41 MB

    // ---- CSR build ----
    hist2<<<NT * NCHUNK, 256, 0, stream>>>(edg, counts16);
    sumtot16<<<(NT * NN / 2 + 255) / 256, 256, 0, stream>>>(counts16, totals);
    scan_kernel<<<NT, 1024, 0, stream>>>(totals, row_ptr);
    place2<<<NT * NCHUNK, 256, 0, stream>>>(edg, counts16, row_ptr, csr_src);
    precompute_u<<<NT, 128, 0, stream>>>(W1, as1, ad1, W2, as2, ad2, u1s, u1d, u2s, u2d);

    // ---- Layer 1 ----
    dim3 gtn((NN + 255) / 256, NT);
    layer1_fused<<<gtn, 256, 0, stream>>>(x, csr_src, row_ptr, u1s, u1d, g1);
    transform1<<<(4 * NN * 32 + 255) / 256, 256, 0, stream>>>(g1, W1, b1, x1);

    // ---- Layer 2 ----
    scores2<<<gtn, 256, 0, stream>>>(x1, u2s, u2d, (float4*)ss, (float4*)ds);
    alpha2s<<<gtn, 256, 0, stream>>>(csr_src, row_ptr, (const float4*)ss, (const float4*)ds,
                                     alpha, dn2);
    layer2_full<<<dim3(NN / 8, 4), 256, 0, stream>>>(x1, csr_src, row_ptr, alpha, dn2, W2, b2,
                                                     out);
}

// Round 10
// 662.772 us; speedup vs baseline: 1.1268x; 1.0810x over previous
//
#include <hip/hip_runtime.h>
#include <hip/hip_fp16.h>
#include <math.h>

#define NN 20000
#define NE 320000
#define NT 16
#define NEG 0.2f
#define NCHUNK 16
#define CHSZ (NE / NCHUNK)   // 20000

__device__ __forceinline__ int d_src_of(int t) { return t < 4 ? t : (t - 4) / 3; }
__device__ __forceinline__ int d_dst_of(int t) {
    if (t < 4) return t;
    int i = t - 4, s = i / 3, j = i % 3;
    return j + (j >= s ? 1 : 0);
}

// ============ CSR 1: per-(type,chunk) histogram -> u16 packed counts ============
__global__ void hist2(const int* __restrict__ edges, unsigned short* __restrict__ counts16) {
    int t = blockIdx.x >> 4, chunk = blockIdx.x & 15;
    __shared__ unsigned h[NN / 2];  // 40 KB, two u16 bins per word
    for (int i = threadIdx.x; i < NN / 2; i += 256) h[i] = 0;
    __syncthreads();
    const int* dstp = edges + (size_t)t * 2 * NE + NE + chunk * CHSZ;
    for (int e = threadIdx.x; e < CHSZ; e += 256) {
        int d = dstp[e];
        atomicAdd(&h[d >> 1], (d & 1) ? 0x10000u : 1u);
    }
    __syncthreads();
    unsigned* cout = (unsigned*)(counts16 + ((size_t)t * NCHUNK + chunk) * NN);
    for (int i = threadIdx.x; i < NN / 2; i += 256) cout[i] = h[i];
}

// ============ CSR 2: totals + in-place exclusive prefix over chunks (packed) ============
__global__ void sumtot16(unsigned short* __restrict__ counts16, int* __restrict__ totals) {
    int idx = blockIdx.x * 256 + threadIdx.x;  // t*(NN/2) + i
    if (idx >= NT * NN / 2) return;
    int t = idx / (NN / 2), i = idx % (NN / 2);
    unsigned* base = (unsigned*)counts16 + (size_t)t * NCHUNK * (NN / 2) + i;
    unsigned run0 = 0, run1 = 0;
#pragma unroll
    for (int c = 0; c < NCHUNK; c++) {
        unsigned v = base[(size_t)c * (NN / 2)];
        base[(size_t)c * (NN / 2)] = run0 | (run1 << 16);
        run0 += v & 0xffffu;
        run1 += v >> 16;
    }
    totals[t * NN + 2 * i]     = (int)run0;
    totals[t * NN + 2 * i + 1] = (int)run1;
}

// ============ CSR 3: exclusive scan per type (1024 threads) ============
__global__ void scan_kernel(const int* __restrict__ totals, int* __restrict__ row_ptr) {
    int t = blockIdx.x, tid = threadIdx.x;
    __shared__ int buf[1024];
    int running = 0;
    for (int base = 0; base < NN; base += 1024) {
        int i = base + tid;
        int v = (i < NN) ? totals[t * NN + i] : 0;
        buf[tid] = v;
        __syncthreads();
        for (int off = 1; off < 1024; off <<= 1) {
            int x = (tid >= off) ? buf[tid - off] : 0;
            __syncthreads();
            buf[tid] += x;
            __syncthreads();
        }
        if (i < NN) row_ptr[t * (NN + 1) + i] = running + buf[tid] - v;
        int tot = buf[1023];
        __syncthreads();
        running += tot;
    }
    if (tid == 0) row_ptr[t * (NN + 1) + NN] = running;
}

// ============ CSR 4: placement; type->XCD affinity so CSR region stays in one L2 ============
__global__ void place2(const int* __restrict__ edges, const unsigned short* __restrict__ counts16,
                       const int* __restrict__ row_ptr, int* __restrict__ csr_src) {
    int t = blockIdx.x & 15, chunk = blockIdx.x >> 4;
    __shared__ unsigned cur[NN / 2];
    for (int i = threadIdx.x; i < NN / 2; i += 256) cur[i] = 0;
    __syncthreads();
    const int* srcp = edges + (size_t)t * 2 * NE + chunk * CHSZ;
    const int* dstp = srcp + NE;
    const unsigned short* cb = counts16 + ((size_t)t * NCHUNK + chunk) * NN;
    const int* rp = row_ptr + t * (NN + 1);
    int* cs = csr_src + (size_t)t * NE;
    for (int e = threadIdx.x; e < CHSZ; e += 256) {
        int d = dstp[e];
        unsigned old = atomicAdd(&cur[d >> 1], (d & 1) ? 0x10000u : 1u);
        int off = (d & 1) ? (int)(old >> 16) : (int)(old & 0xffffu);
        cs[rp[d] + (int)cb[d] + off] = srcp[e];
    }
}

// ============ precompute u = reduce(W * a) over c ============
__global__ void precompute_u(const float* __restrict__ W1, const float* __restrict__ as1,
                             const float* __restrict__ ad1, const float* __restrict__ W2,
                             const float* __restrict__ as2, const float* __restrict__ ad2,
                             float* __restrict__ u1s, float* __restrict__ u1d,
                             float* __restrict__ u2s, float* __restrict__ u2d) {
    int t = blockIdx.x, tid = threadIdx.x;  // 128 threads
    int k = tid >> 2, h = tid & 3;
    float ss = 0.f, dd = 0.f;
    for (int c = 0; c < 32; c++) {
        float w = W2[(size_t)t * 4096 + k * 128 + h * 32 + c];
        ss += w * as2[t * 128 + h * 32 + c];
        dd += w * ad2[t * 128 + h * 32 + c];
    }
    u2s[(t * 32 + k) * 4 + h] = ss;
    u2d[(t * 32 + k) * 4 + h] = dd;
    if (tid < 4) {
        int hh = tid;
        float s1 = 0.f, d1 = 0.f;
        for (int c = 0; c < 32; c++) {
            float w = W1[t * 128 + hh * 32 + c];
            s1 += w * as1[t * 128 + hh * 32 + c];
            d1 += w * ad1[t * 128 + hh * 32 + c];
        }
        u1s[t * 4 + hh] = s1;
        u1d[t * 4 + hh] = d1;
    }
}

// ============ Layer 1: fused attention + aggregation (no max-sub: |logit| < ~1) ============
__global__ void layer1_fused(const float* __restrict__ x, const int* __restrict__ csr_src,
                             const int* __restrict__ row_ptr, const float* __restrict__ u1s,
                             const float* __restrict__ u1d, float4* __restrict__ g1) {
    int t = blockIdx.y;
    int d = blockIdx.x * 256 + threadIdx.x;
    if (d >= NN) return;
    int sc = d_src_of(t), dc = d_dst_of(t);
    float xd = x[dc * NN + d];
    float4 usv = ((const float4*)u1s)[t];
    float4 udv = ((const float4*)u1d)[t];
    float us[4] = {usv.x, usv.y, usv.z, usv.w};
    float dl[4] = {xd * udv.x, xd * udv.y, xd * udv.z, xd * udv.w};
    int rb = row_ptr[t * (NN + 1) + d], re = row_ptr[t * (NN + 1) + d + 1];
    float dn[4] = {0, 0, 0, 0}, a[4] = {0, 0, 0, 0};
    const int* cs = csr_src + (size_t)t * NE;
#pragma unroll 2
    for (int i = rb; i < re; i++) {
        int s = cs[i];
        float xs = x[sc * NN + s];
#pragma unroll
        for (int h = 0; h < 4; h++) {
            float l = xs * us[h] + dl[h];
            l = l > 0.f ? l : NEG * l;
            float p = __expf(l);
            dn[h] += p;
            a[h] += p * xs;
        }
    }
    float4 g;
    g.x = (re > rb) ? a[0] / dn[0] : 0.f;
    g.y = (re > rb) ? a[1] / dn[1] : 0.f;
    g.z = (re > rb) ? a[2] / dn[2] : 0.f;
    g.w = (re > rb) ? a[3] / dn[3] : 0.f;
    g1[t * NN + d] = g;
}

// ============ Layer 1 transform ============
__global__ void transform1(const float4* __restrict__ g1, const float* __restrict__ W1,
                           const float* __restrict__ b1, float* __restrict__ x1) {
    int idx = blockIdx.x * 256 + threadIdx.x;  // [ch][n][c]
    if (idx >= 4 * NN * 32) return;
    int c = idx & 31;
    int n = (idx >> 5) % NN;
    int ch = idx / (NN * 32);
    float sum = 0.f, bs = 0.f;
#pragma unroll
    for (int t = 0; t < NT; t++) {
        if (d_dst_of(t) == ch) {
            float4 g = g1[t * NN + n];
            const float* w = W1 + t * 128 + c;
            sum += 0.25f * (g.x * w[0] + g.y * w[32] + g.z * w[64] + g.w * w[96]);
            bs += b1[t * 32 + c];
        }
    }
    float v = 0.25f * (sum + bs);
    x1[idx] = v > 0.f ? v : 0.f;
}

// ============ Layer 2 scores (float4 k-loop) ============
__global__ void scores2(const float* __restrict__ x1, const float* __restrict__ u2s,
                        const float* __restrict__ u2d, float4* __restrict__ ss,
                        float4* __restrict__ ds) {
    int t = blockIdx.y;
    int n = blockIdx.x * 256 + threadIdx.x;
    if (n >= NN) return;
    int sc = d_src_of(t), dc = d_dst_of(t);
    const float4* xsr = (const float4*)(x1 + ((size_t)sc * NN + n) * 32);
    const float4* xdr = (const float4*)(x1 + ((size_t)dc * NN + n) * 32);
    const float4* us = (const float4*)(u2s + (size_t)t * 128);  // row k = float4 over h
    const float4* ud = (const float4*)(u2d + (size_t)t * 128);
    float4 s4 = make_float4(0.f, 0.f, 0.f, 0.f);
    float4 d4 = make_float4(0.f, 0.f, 0.f, 0.f);
#pragma unroll
    for (int kq = 0; kq < 8; kq++) {
        float4 xs = xsr[kq], xd = xdr[kq];
#pragma unroll
        for (int m = 0; m < 4; m++) {
            float xsk = (&xs.x)[m], xdk = (&xd.x)[m];
            float4 u = us[4 * kq + m], v = ud[4 * kq + m];
            s4.x += xsk * u.x; s4.y += xsk * u.y; s4.z += xsk * u.z; s4.w += xsk * u.w;
            d4.x += xdk * v.x; d4.y += xdk * v.y; d4.z += xdk * v.z; d4.w += xdk * v.w;
        }
    }
    ss[t * NN + n] = s4;
    ds[t * NN + n] = d4;
}

// ============ Layer 2a: SINGLE-PASS unnormalized exp (half4) + per-dst denom ============
// normal stores — alpha must stay L2-resident for layer2_full (r8/r9 lesson: nt anywhere
// in this chain forces cs/alpha into HBM round-trips, +68 MB FETCH)
__global__ void alpha2s(const int* __restrict__ csr_src, const int* __restrict__ row_ptr,
                        const float4* __restrict__ ss, const float4* __restrict__ ds,
                        unsigned long long* __restrict__ alpha, float4* __restrict__ dn2) {
    int t = blockIdx.y;
    int d = blockIdx.x * 256 + threadIdx.x;
    if (d >= NN) return;
    float4 dsv = ds[t * NN + d];
    float dl[4] = {dsv.x, dsv.y, dsv.z, dsv.w};
    int rb = row_ptr[t * (NN + 1) + d], re = row_ptr[t * (NN + 1) + d + 1];
    const int* cs = csr_src + (size_t)t * NE;
    unsigned long long* ap = alpha + (size_t)t * NE;
    float dn[4] = {0, 0, 0, 0};
#pragma unroll 2
    for (int i = rb; i < re; i++) {
        int s = cs[i];
        float4 sv = ss[t * NN + s];
        float p0, p1, p2, p3;
        { float l = sv.x + dl[0]; l = l > 0.f ? l : NEG * l; p0 = __expf(l); }
        { float l = sv.y + dl[1]; l = l > 0.f ? l : NEG * l; p1 = __expf(l); }
        { float l = sv.z + dl[2]; l = l > 0.f ? l : NEG * l; p2 = __expf(l); }
        { float l = sv.w + dl[3]; l = l > 0.f ? l : NEG * l; p3 = __expf(l); }
        dn[0] += p0; dn[1] += p1; dn[2] += p2; dn[3] += p3;
        __half2 h01 = __floats2half2_rn(p0, p1);
        __half2 h23 = __floats2half2_rn(p2, p3);
        ap[i] = (unsigned long long)(*(unsigned*)&h01) |
                ((unsigned long long)(*(unsigned*)&h23) << 32);
    }
    dn2[t * NN + d] = make_float4(dn[0], dn[1], dn[2], dn[3]);
}

// ============ Layer 2b: gather+FMA aggregation + denom + W2 + bias + means + relu ============
// ROUND-6 BODY (best measured: 215us) + ONE change: 1D grid with channel->XCD affinity
// (xcd = b&7, ch = xcd>>1) so each XCD's L2 holds only 1-2 of the four 2.56MB x1 source
// tables instead of all four + streams (round-6 FETCH showed ~150MB of x1 re-misses).
// No nt loads (r8/r9 lesson), no transposed LDS staging (r9 lesson: 8-way LDS conflicts).
// NOTE: phase loop MUST NOT be unrolled — unrolling merges 4 phases' staging loads and
// blows past 256 VGPRs into scratch spills (round-4 regression: 2.9 GB scratch writes).
__global__ __launch_bounds__(256) void layer2_full(
    const float* __restrict__ x1, const int* __restrict__ csr_src,
    const int* __restrict__ row_ptr, const unsigned long long* __restrict__ alpha,
    const float4* __restrict__ dn2, const float* __restrict__ W2,
    const float* __restrict__ b2, float* __restrict__ out) {
    int b = blockIdx.x;
    int xcd = b & 7;
    int ch = xcd >> 1;
    int dt = (b >> 3) * 2 + (xcd & 1);   // 0..2499, each (ch,dt) exactly once
    int grp = threadIdx.x >> 5, lane = threadIdx.x & 31;
    int d = dt * 8 + grp;
    __shared__ float4 W2s[1024];     // 16 KB
    __shared__ float gl[8 * 128];    // 4 KB  -> 20 KB total
    const float* W2f = (const float*)W2s;
    float o = 0.f, bsum = 0.f;
#pragma unroll 1
    for (int j = 0; j < 4; j++) {
        int t, sc;
        if (j == 0) { t = ch; sc = ch; }
        else {
            int s = (j - 1) + ((j - 1) >= ch ? 1 : 0);        // enumerate s != ch
            t = 4 + s * 3 + (ch > s ? ch - 1 : ch);
            sc = s;
        }
        __syncthreads();  // protect W2s/gl from previous phase readers
        const float4* wsrc = (const float4*)(W2 + (size_t)t * 4096);
#pragma unroll
        for (int i = 0; i < 4; i++) W2s[threadIdx.x + i * 256] = wsrc[threadIdx.x + i * 256];
        bsum += b2[t * 32 + lane];
        int rb = row_ptr[t * (NN + 1) + d], re = row_ptr[t * (NN + 1) + d + 1];
        float val[4] = {0, 0, 0, 0};
        const int* cs = csr_src + (size_t)t * NE;
        const unsigned long long* ap = alpha + (size_t)t * NE;
        const float* xb = x1 + (size_t)sc * NN * 32;
        int i = rb;
        for (; i + 4 <= re; i += 4) {  // 4 independent gather chains in flight
            int s0 = cs[i], s1 = cs[i + 1], s2 = cs[i + 2], s3 = cs[i + 3];
            unsigned long long a0 = ap[i], a1 = ap[i + 1], a2 = ap[i + 2], a3 = ap[i + 3];
            float x0 = xb[s0 * 32 + lane];
            float x1v = xb[s1 * 32 + lane];
            float x2 = xb[s2 * 32 + lane];
            float x3 = xb[s3 * 32 + lane];
            unsigned lo, hi;
            float2 p01, p23;
            lo = (unsigned)a0; hi = (unsigned)(a0 >> 32);
            p01 = __half22float2(*(const __half2*)&lo); p23 = __half22float2(*(const __half2*)&hi);
            val[0] += p01.x * x0; val[1] += p01.y * x0; val[2] += p23.x * x0; val[3] += p23.y * x0;
            lo = (unsigned)a1; hi = (unsigned)(a1 >> 32);
            p01 = __half22float2(*(const __half2*)&lo); p23 = __half22float2(*(const __half2*)&hi);
            val[0] += p01.x * x1v; val[1] += p01.y * x1v; val[2] += p23.x * x1v; val[3] += p23.y * x1v;
            lo = (unsigned)a2; hi = (unsigned)(a2 >> 32);
            p01 = __half22float2(*(const __half2*)&lo); p23 = __half22float2(*(const __half2*)&hi);
            val[0] += p01.x * x2; val[1] += p01.y * x2; val[2] += p23.x * x2; val[3] += p23.y * x2;
            lo = (unsigned)a3; hi = (unsigned)(a3 >> 32);
            p01 = __half22float2(*(const __half2*)&lo); p23 = __half22float2(*(const __half2*)&hi);
            val[0] += p01.x * x3; val[1] += p01.y * x3; val[2] += p23.x * x3; val[3] += p23.y * x3;
        }
        for (; i < re; i++) {
            int s = cs[i];
            unsigned long long a = ap[i];
            float xk = xb[s * 32 + lane];
            unsigned lo = (unsigned)a, hi = (unsigned)(a >> 32);
            float2 p01 = __half22float2(*(const __half2*)&lo);
            float2 p23 = __half22float2(*(const __half2*)&hi);
            val[0] += p01.x * xk; val[1] += p01.y * xk; val[2] += p23.x * xk; val[3] += p23.y * xk;
        }
        float4 dnv = dn2[t * NN + d];
        float r0 = dnv.x > 0.f ? 1.f / dnv.x : 0.f;
        float r1 = dnv.y > 0.f ? 1.f / dnv.y : 0.f;
        float r2 = dnv.z > 0.f ? 1.f / dnv.z : 0.f;
        float r3 = dnv.w > 0.f ? 1.f / dnv.w : 0.f;
        gl[grp * 128 +       lane] = val[0] * r0;
        gl[grp * 128 +  32 + lane] = val[1] * r1;
        gl[grp * 128 +  64 + lane] = val[2] * r2;
        gl[grp * 128 +  96 + lane] = val[3] * r3;
        __syncthreads();
        float acc = 0.f;
#pragma unroll 4
        for (int k = 0; k < 32; k++) {
            const float* gb = gl + grp * 128 + k;
            const float* wb = W2f + k * 128 + lane;
            acc += gb[0] * wb[0] + gb[32] * wb[32] + gb[64] * wb[64] + gb[96] * wb[96];
        }
        o += acc;
    }
    float r = o * 0.0625f + bsum * 0.25f;  // (/H=4 then /4 types) ; (bias sum)/4
    r = r > 0.f ? r : 0.f;
    out[(size_t)d * 128 + ch * 32 + lane] = r;
}

extern "C" void kernel_launch(void* const* d_in, const int* in_sizes, int n_in,
                              void* d_out, int out_size, void* d_ws, size_t ws_size,
                              hipStream_t stream) {
    const float* x   = (const float*)d_in[0];
    const int*   edg = (const int*)d_in[1];
    const float* W1  = (const float*)d_in[2];
    const float* as1 = (const float*)d_in[3];
    const float* ad1 = (const float*)d_in[4];
    const float* b1  = (const float*)d_in[5];
    const float* W2  = (const float*)d_in[6];
    const float* as2 = (const float*)d_in[7];
    const float* ad2 = (const float*)d_in[8];
    const float* b2  = (const float*)d_in[9];
    float* out = (float*)d_out;

    char* w = (char*)d_ws;
    auto carve = [&](size_t bytes) {
        void* p = (void*)w;
        w += (bytes + 255) & ~(size_t)255;
        return p;
    };
    int*   csr_src = (int*)carve((size_t)NT * NE * 4);        // 20.5 MB
    int*   row_ptr = (int*)carve((size_t)NT * (NN + 1) * 4);  // 1.3 MB
    float* u1s     = (float*)carve(NT * 4 * 4);
    float* u1d     = (float*)carve(NT * 4 * 4);
    float* u2s     = (float*)carve(NT * 32 * 4 * 4);
    float* u2d     = (float*)carve(NT * 32 * 4 * 4);
    float* x1      = (float*)carve((size_t)4 * NN * 32 * 4);  // 10.2 MB
    float* ss      = (float*)carve((size_t)NT * NN * 4 * 4);  // 5.1 MB
    float* ds      = (float*)carve((size_t)NT * NN * 4 * 4);  // 5.1 MB
    float4* dn2    = (float4*)carve((size_t)NT * NN * 16);    // 5.1 MB
    // time-multiplexed region (41 MB): {counts16+totals} -> {g1} -> {alpha}
    char* region   = (char*)carve((size_t)NT * NE * 8);
    unsigned short* counts16 = (unsigned short*)region;                       // 10.2 MB
    int*            totals   = (int*)(region + (size_t)NT * NCHUNK * NN * 2); // 1.3 MB
    float4*         g1       = (float4*)region;                               // 5.1 MB
    unsigned long long* alpha = (unsigned long long*)region;                  // 41 MB

    // ---- CSR build ----
    hist2<<<NT * NCHUNK, 256, 0, stream>>>(edg, counts16);
    sumtot16<<<(NT * NN / 2 + 255) / 256, 256, 0, stream>>>(counts16, totals);
    scan_kernel<<<NT, 1024, 0, stream>>>(totals, row_ptr);
    place2<<<NT * NCHUNK, 256, 0, stream>>>(edg, counts16, row_ptr, csr_src);
    precompute_u<<<NT, 128, 0, stream>>>(W1, as1, ad1, W2, as2, ad2, u1s, u1d, u2s, u2d);

    // ---- Layer 1 ----
    dim3 gtn((NN + 255) / 256, NT);
    layer1_fused<<<gtn, 256, 0, stream>>>(x, csr_src, row_ptr, u1s, u1d, g1);
    transform1<<<(4 * NN * 32 + 255) / 256, 256, 0, stream>>>(g1, W1, b1, x1);

    // ---- Layer 2 ----
    scores2<<<gtn, 256, 0, stream>>>(x1, u2s, u2d, (float4*)ss, (float4*)ds);
    alpha2s<<<gtn, 256, 0, stream>>>(csr_src, row_ptr, (const float4*)ss, (const float4*)ds,
                                     alpha, dn2);
    layer2_full<<<10000, 256, 0, stream>>>(x1, csr_src, row_ptr, alpha, dn2, W2, b2, out);
}

// Round 11
// 650.058 us; speedup vs baseline: 1.1488x; 1.0196x over previous
//
#include <hip/hip_runtime.h>
#include <hip/hip_fp16.h>
#include <math.h>

#define NN 20000
#define NE 320000
#define NT 16
#define NEG 0.2f
#define NCHUNK 16
#define CHSZ (NE / NCHUNK)   // 20000

__device__ __forceinline__ int d_src_of(int t) { return t < 4 ? t : (t - 4) / 3; }
__device__ __forceinline__ int d_dst_of(int t) {
    if (t < 4) return t;
    int i = t - 4, s = i / 3, j = i % 3;
    return j + (j >= s ? 1 : 0);
}

// ============ CSR 1: per-(type,chunk) histogram -> u16 packed counts ============
__global__ void hist2(const int* __restrict__ edges, unsigned short* __restrict__ counts16) {
    int t = blockIdx.x >> 4, chunk = blockIdx.x & 15;
    __shared__ unsigned h[NN / 2];  // 40 KB, two u16 bins per word
    for (int i = threadIdx.x; i < NN / 2; i += 256) h[i] = 0;
    __syncthreads();
    const int* dstp = edges + (size_t)t * 2 * NE + NE + chunk * CHSZ;
    for (int e = threadIdx.x; e < CHSZ; e += 256) {
        int d = dstp[e];
        atomicAdd(&h[d >> 1], (d & 1) ? 0x10000u : 1u);
    }
    __syncthreads();
    unsigned* cout = (unsigned*)(counts16 + ((size_t)t * NCHUNK + chunk) * NN);
    for (int i = threadIdx.x; i < NN / 2; i += 256) cout[i] = h[i];
}

// ============ CSR 2: totals + in-place exclusive prefix over chunks (packed) ============
__global__ void sumtot16(unsigned short* __restrict__ counts16, int* __restrict__ totals) {
    int idx = blockIdx.x * 256 + threadIdx.x;  // t*(NN/2) + i
    if (idx >= NT * NN / 2) return;
    int t = idx / (NN / 2), i = idx % (NN / 2);
    unsigned* base = (unsigned*)counts16 + (size_t)t * NCHUNK * (NN / 2) + i;
    unsigned run0 = 0, run1 = 0;
#pragma unroll
    for (int c = 0; c < NCHUNK; c++) {
        unsigned v = base[(size_t)c * (NN / 2)];
        base[(size_t)c * (NN / 2)] = run0 | (run1 << 16);
        run0 += v & 0xffffu;
        run1 += v >> 16;
    }
    totals[t * NN + 2 * i]     = (int)run0;
    totals[t * NN + 2 * i + 1] = (int)run1;
}

// ============ CSR 3: exclusive scan per type (1024 threads) ============
__global__ void scan_kernel(const int* __restrict__ totals, int* __restrict__ row_ptr) {
    int t = blockIdx.x, tid = threadIdx.x;
    __shared__ int buf[1024];
    int running = 0;
    for (int base = 0; base < NN; base += 1024) {
        int i = base + tid;
        int v = (i < NN) ? totals[t * NN + i] : 0;
        buf[tid] = v;
        __syncthreads();
        for (int off = 1; off < 1024; off <<= 1) {
            int x = (tid >= off) ? buf[tid - off] : 0;
            __syncthreads();
            buf[tid] += x;
            __syncthreads();
        }
        if (i < NN) row_ptr[t * (NN + 1) + i] = running + buf[tid] - v;
        int tot = buf[1023];
        __syncthreads();
        running += tot;
    }
    if (tid == 0) row_ptr[t * (NN + 1) + NN] = running;
}

// ============ CSR 4: placement; type->XCD affinity so CSR region stays in one L2 ============
__global__ void place2(const int* __restrict__ edges, const unsigned short* __restrict__ counts16,
                       const int* __restrict__ row_ptr, int* __restrict__ csr_src) {
    int t = blockIdx.x & 15, chunk = blockIdx.x >> 4;
    __shared__ unsigned cur[NN / 2];
    for (int i = threadIdx.x; i < NN / 2; i += 256) cur[i] = 0;
    __syncthreads();
    const int* srcp = edges + (size_t)t * 2 * NE + chunk * CHSZ;
    const int* dstp = srcp + NE;
    const unsigned short* cb = counts16 + ((size_t)t * NCHUNK + chunk) * NN;
    const int* rp = row_ptr + t * (NN + 1);
    int* cs = csr_src + (size_t)t * NE;
    for (int e = threadIdx.x; e < CHSZ; e += 256) {
        int d = dstp[e];
        unsigned old = atomicAdd(&cur[d >> 1], (d & 1) ? 0x10000u : 1u);
        int off = (d & 1) ? (int)(old >> 16) : (int)(old & 0xffffu);
        cs[rp[d] + (int)cb[d] + off] = srcp[e];
    }
}

// ============ precompute u = reduce(W * a) over c ============
__global__ void precompute_u(const float* __restrict__ W1, const float* __restrict__ as1,
                             const float* __restrict__ ad1, const float* __restrict__ W2,
                             const float* __restrict__ as2, const float* __restrict__ ad2,
                             float* __restrict__ u1s, float* __restrict__ u1d,
                             float* __restrict__ u2s, float* __restrict__ u2d) {
    int t = blockIdx.x, tid = threadIdx.x;  // 128 threads
    int k = tid >> 2, h = tid & 3;
    float ss = 0.f, dd = 0.f;
    for (int c = 0; c < 32; c++) {
        float w = W2[(size_t)t * 4096 + k * 128 + h * 32 + c];
        ss += w * as2[t * 128 + h * 32 + c];
        dd += w * ad2[t * 128 + h * 32 + c];
    }
    u2s[(t * 32 + k) * 4 + h] = ss;
    u2d[(t * 32 + k) * 4 + h] = dd;
    if (tid < 4) {
        int hh = tid;
        float s1 = 0.f, d1 = 0.f;
        for (int c = 0; c < 32; c++) {
            float w = W1[t * 128 + hh * 32 + c];
            s1 += w * as1[t * 128 + hh * 32 + c];
            d1 += w * ad1[t * 128 + hh * 32 + c];
        }
        u1s[t * 4 + hh] = s1;
        u1d[t * 4 + hh] = d1;
    }
}

// ============ Layer 1: fused attention + aggregation (no max-sub: |logit| < ~1) ============
__global__ void layer1_fused(const float* __restrict__ x, const int* __restrict__ csr_src,
                             const int* __restrict__ row_ptr, const float* __restrict__ u1s,
                             const float* __restrict__ u1d, float4* __restrict__ g1) {
    int t = blockIdx.y;
    int d = blockIdx.x * 256 + threadIdx.x;
    if (d >= NN) return;
    int sc = d_src_of(t), dc = d_dst_of(t);
    float xd = x[dc * NN + d];
    float4 usv = ((const float4*)u1s)[t];
    float4 udv = ((const float4*)u1d)[t];
    float us[4] = {usv.x, usv.y, usv.z, usv.w};
    float dl[4] = {xd * udv.x, xd * udv.y, xd * udv.z, xd * udv.w};
    int rb = row_ptr[t * (NN + 1) + d], re = row_ptr[t * (NN + 1) + d + 1];
    float dn[4] = {0, 0, 0, 0}, a[4] = {0, 0, 0, 0};
    const int* cs = csr_src + (size_t)t * NE;
#pragma unroll 2
    for (int i = rb; i < re; i++) {
        int s = cs[i];
        float xs = x[sc * NN + s];
#pragma unroll
        for (int h = 0; h < 4; h++) {
            float l = xs * us[h] + dl[h];
            l = l > 0.f ? l : NEG * l;
            float p = __expf(l);
            dn[h] += p;
            a[h] += p * xs;
        }
    }
    float4 g;
    g.x = (re > rb) ? a[0] / dn[0] : 0.f;
    g.y = (re > rb) ? a[1] / dn[1] : 0.f;
    g.z = (re > rb) ? a[2] / dn[2] : 0.f;
    g.w = (re > rb) ? a[3] / dn[3] : 0.f;
    g1[t * NN + d] = g;
}

// ============ Layer 1 transform ============
__global__ void transform1(const float4* __restrict__ g1, const float* __restrict__ W1,
                           const float* __restrict__ b1, float* __restrict__ x1) {
    int idx = blockIdx.x * 256 + threadIdx.x;  // [ch][n][c]
    if (idx >= 4 * NN * 32) return;
    int c = idx & 31;
    int n = (idx >> 5) % NN;
    int ch = idx / (NN * 32);
    float sum = 0.f, bs = 0.f;
#pragma unroll
    for (int t = 0; t < NT; t++) {
        if (d_dst_of(t) == ch) {
            float4 g = g1[t * NN + n];
            const float* w = W1 + t * 128 + c;
            sum += 0.25f * (g.x * w[0] + g.y * w[32] + g.z * w[64] + g.w * w[96]);
            bs += b1[t * 32 + c];
        }
    }
    float v = 0.25f * (sum + bs);
    x1[idx] = v > 0.f ? v : 0.f;
}

// ============ Layer 2 scores (float4 k-loop) ============
__global__ void scores2(const float* __restrict__ x1, const float* __restrict__ u2s,
                        const float* __restrict__ u2d, float4* __restrict__ ss,
                        float4* __restrict__ ds) {
    int t = blockIdx.y;
    int n = blockIdx.x * 256 + threadIdx.x;
    if (n >= NN) return;
    int sc = d_src_of(t), dc = d_dst_of(t);
    const float4* xsr = (const float4*)(x1 + ((size_t)sc * NN + n) * 32);
    const float4* xdr = (const float4*)(x1 + ((size_t)dc * NN + n) * 32);
    const float4* us = (const float4*)(u2s + (size_t)t * 128);  // row k = float4 over h
    const float4* ud = (const float4*)(u2d + (size_t)t * 128);
    float4 s4 = make_float4(0.f, 0.f, 0.f, 0.f);
    float4 d4 = make_float4(0.f, 0.f, 0.f, 0.f);
#pragma unroll
    for (int kq = 0; kq < 8; kq++) {
        float4 xs = xsr[kq], xd = xdr[kq];
#pragma unroll
        for (int m = 0; m < 4; m++) {
            float xsk = (&xs.x)[m], xdk = (&xd.x)[m];
            float4 u = us[4 * kq + m], v = ud[4 * kq + m];
            s4.x += xsk * u.x; s4.y += xsk * u.y; s4.z += xsk * u.z; s4.w += xsk * u.w;
            d4.x += xdk * v.x; d4.y += xdk * v.y; d4.z += xdk * v.z; d4.w += xdk * v.w;
        }
    }
    ss[t * NN + n] = s4;
    ds[t * NN + n] = d4;
}

// ============ Layer 2: FULLY-FUSED softmax + aggregation + W2 + bias + means + relu ======
// alpha2s pass eliminated: since normalization divides AFTER the edge loop, dn[h] is
// accumulated in the same pass as val[h]; p = exp(lrelu(ss[s]+ds[d])) computed inline.
// ss gather is group-uniform (2 addrs/wave, L1 broadcast); exp redundancy across the
// group's 32 lanes is free (one wave instruction). lrelu = max(l, 0.2*l).
// No nt loads (r8/r9 lesson), no transposed LDS staging (r9: 8-way LDS conflicts).
// NOTE: phase loop MUST NOT be unrolled — unrolling merges 4 phases' staging loads and
// blows past 256 VGPRs into scratch spills (round-4 regression: 2.9 GB scratch writes).
__global__ __launch_bounds__(256) void layer2_full(
    const float* __restrict__ x1, const int* __restrict__ csr_src,
    const int* __restrict__ row_ptr, const float4* __restrict__ ss,
    const float4* __restrict__ ds, const float* __restrict__ W2,
    const float* __restrict__ b2, float* __restrict__ out) {
    int b = blockIdx.x;
    int xcd = b & 7;
    int ch = xcd >> 1;
    int dt = (b >> 3) * 2 + (xcd & 1);   // 0..2499, each (ch,dt) exactly once
    int grp = threadIdx.x >> 5, lane = threadIdx.x & 31;
    int d = dt * 8 + grp;
    __shared__ float4 W2s[1024];     // 16 KB
    __shared__ float gl[8 * 128];    // 4 KB  -> 20 KB total
    const float* W2f = (const float*)W2s;
    float o = 0.f, bsum = 0.f;
#pragma unroll 1
    for (int j = 0; j < 4; j++) {
        int t, sc;
        if (j == 0) { t = ch; sc = ch; }
        else {
            int s = (j - 1) + ((j - 1) >= ch ? 1 : 0);        // enumerate s != ch
            t = 4 + s * 3 + (ch > s ? ch - 1 : ch);
            sc = s;
        }
        __syncthreads();  // protect W2s/gl from previous phase readers
        const float4* wsrc = (const float4*)(W2 + (size_t)t * 4096);
#pragma unroll
        for (int i = 0; i < 4; i++) W2s[threadIdx.x + i * 256] = wsrc[threadIdx.x + i * 256];
        bsum += b2[t * 32 + lane];
        float4 dsv = ds[t * NN + d];
        float dl[4] = {dsv.x, dsv.y, dsv.z, dsv.w};
        int rb = row_ptr[t * (NN + 1) + d], re = row_ptr[t * (NN + 1) + d + 1];
        float val[4] = {0, 0, 0, 0};
        float dn[4] = {0, 0, 0, 0};
        const int* cs = csr_src + (size_t)t * NE;
        const float4* ssb = ss + (size_t)t * NN;
        const float* xb = x1 + (size_t)sc * NN * 32;
        int i = rb;
        for (; i + 4 <= re; i += 4) {  // 4 independent gather chains in flight
            int sA[4];
            float4 svA[4];
            float xA[4];
#pragma unroll
            for (int u = 0; u < 4; u++) sA[u] = cs[i + u];
#pragma unroll
            for (int u = 0; u < 4; u++) {
                svA[u] = ssb[sA[u]];           // group-uniform 16B, L1 broadcast
                xA[u] = xb[sA[u] * 32 + lane]; // coalesced 128B per group
            }
#pragma unroll
            for (int u = 0; u < 4; u++) {
                float xk = xA[u];
                const float* sl = &svA[u].x;
#pragma unroll
                for (int h = 0; h < 4; h++) {
                    float l = sl[h] + dl[h];
                    l = fmaxf(l, NEG * l);     // leaky-relu, 2 insts
                    float p = __expf(l);
                    dn[h] += p;
                    val[h] += p * xk;
                }
            }
        }
        for (; i < re; i++) {
            int s = cs[i];
            float4 sv = ssb[s];
            float xk = xb[s * 32 + lane];
            const float* sl = &sv.x;
#pragma unroll
            for (int h = 0; h < 4; h++) {
                float l = sl[h] + dl[h];
                l = fmaxf(l, NEG * l);
                float p = __expf(l);
                dn[h] += p;
                val[h] += p * xk;
            }
        }
        float r0 = (re > rb) ? 1.f / dn[0] : 0.f;
        float r1 = (re > rb) ? 1.f / dn[1] : 0.f;
        float r2 = (re > rb) ? 1.f / dn[2] : 0.f;
        float r3 = (re > rb) ? 1.f / dn[3] : 0.f;
        gl[grp * 128 +       lane] = val[0] * r0;
        gl[grp * 128 +  32 + lane] = val[1] * r1;
        gl[grp * 128 +  64 + lane] = val[2] * r2;
        gl[grp * 128 +  96 + lane] = val[3] * r3;
        __syncthreads();
        float acc = 0.f;
#pragma unroll 4
        for (int k = 0; k < 32; k++) {
            const float* gb = gl + grp * 128 + k;
            const float* wb = W2f + k * 128 + lane;
            acc += gb[0] * wb[0] + gb[32] * wb[32] + gb[64] * wb[64] + gb[96] * wb[96];
        }
        o += acc;
    }
    float r = o * 0.0625f + bsum * 0.25f;  // (/H=4 then /4 types) ; (bias sum)/4
    r = r > 0.f ? r : 0.f;
    out[(size_t)d * 128 + ch * 32 + lane] = r;
}

extern "C" void kernel_launch(void* const* d_in, const int* in_sizes, int n_in,
                              void* d_out, int out_size, void* d_ws, size_t ws_size,
                              hipStream_t stream) {
    const float* x   = (const float*)d_in[0];
    const int*   edg = (const int*)d_in[1];
    const float* W1  = (const float*)d_in[2];
    const float* as1 = (const float*)d_in[3];
    const float* ad1 = (const float*)d_in[4];
    const float* b1  = (const float*)d_in[5];
    const float* W2  = (const float*)d_in[6];
    const float* as2 = (const float*)d_in[7];
    const float* ad2 = (const float*)d_in[8];
    const float* b2  = (const float*)d_in[9];
    float* out = (float*)d_out;

    char* w = (char*)d_ws;
    auto carve = [&](size_t bytes) {
        void* p = (void*)w;
        w += (bytes + 255) & ~(size_t)255;
        return p;
    };
    int*   csr_src = (int*)carve((size_t)NT * NE * 4);        // 20.5 MB
    int*   row_ptr = (int*)carve((size_t)NT * (NN + 1) * 4);  // 1.3 MB
    float* u1s     = (float*)carve(NT * 4 * 4);
    float* u1d     = (float*)carve(NT * 4 * 4);
    float* u2s     = (float*)carve(NT * 32 * 4 * 4);
    float* u2d     = (float*)carve(NT * 32 * 4 * 4);
    float* x1      = (float*)carve((size_t)4 * NN * 32 * 4);  // 10.2 MB
    float* ss      = (float*)carve((size_t)NT * NN * 4 * 4);  // 5.1 MB
    float* ds      = (float*)carve((size_t)NT * NN * 4 * 4);  // 5.1 MB
    // time-multiplexed region: {counts16 10.2MB + totals 1.3MB} -> {g1 5.1MB}
    char* region   = (char*)carve((size_t)NT * NCHUNK * NN * 2 + (size_t)NT * NN * 4 + 512);
    unsigned short* counts16 = (unsigned short*)region;
    int*            totals   = (int*)(region + (size_t)NT * NCHUNK * NN * 2);
    float4*         g1       = (float4*)region;

    // ---- CSR build ----
    hist2<<<NT * NCHUNK, 256, 0, stream>>>(edg, counts16);
    sumtot16<<<(NT * NN / 2 + 255) / 256, 256, 0, stream>>>(counts16, totals);
    scan_kernel<<<NT, 1024, 0, stream>>>(totals, row_ptr);
    place2<<<NT * NCHUNK, 256, 0, stream>>>(edg, counts16, row_ptr, csr_src);
    precompute_u<<<NT, 128, 0, stream>>>(W1, as1, ad1, W2, as2, ad2, u1s, u1d, u2s, u2d);

    // ---- Layer 1 ----
    dim3 gtn((NN + 255) / 256, NT);
    layer1_fused<<<gtn, 256, 0, stream>>>(x, csr_src, row_ptr, u1s, u1d, g1);
    transform1<<<(4 * NN * 32 + 255) / 256, 256, 0, stream>>>(g1, W1, b1, x1);

    // ---- Layer 2 ----
    scores2<<<gtn, 256, 0, stream>>>(x1, u2s, u2d, (float4*)ss, (float4*)ds);
    layer2_full<<<10000, 256, 0, stream>>>(x1, csr_src, row_ptr, (const float4*)ss,
                                           (const float4*)ds, W2, b2, out);
}

// Round 12
// 540.312 us; speedup vs baseline: 1.3822x; 1.2031x over previous
//
#include <hip/hip_runtime.h>
#include <hip/hip_fp16.h>
#include <math.h>

#define NN 20000
#define NE 320000
#define NT 16
#define NEG 0.2f
#define NCHUNK 16
#define CHSZ (NE / NCHUNK)   // 20000

__device__ __forceinline__ int d_src_of(int t) { return t < 4 ? t : (t - 4) / 3; }
__device__ __forceinline__ int d_dst_of(int t) {
    if (t < 4) return t;
    int i = t - 4, s = i / 3, j = i % 3;
    return j + (j >= s ? 1 : 0);
}

// ============ CSR 1: per-(type,chunk) histogram -> u16 packed counts ============
__global__ void hist2(const int* __restrict__ edges, unsigned short* __restrict__ counts16) {
    int t = blockIdx.x >> 4, chunk = blockIdx.x & 15;
    __shared__ unsigned h[NN / 2];  // 40 KB, two u16 bins per word
    for (int i = threadIdx.x; i < NN / 2; i += 256) h[i] = 0;
    __syncthreads();
    const int* dstp = edges + (size_t)t * 2 * NE + NE + chunk * CHSZ;
    for (int e = threadIdx.x; e < CHSZ; e += 256) {
        int d = dstp[e];
        atomicAdd(&h[d >> 1], (d & 1) ? 0x10000u : 1u);
    }
    __syncthreads();
    unsigned* cout = (unsigned*)(counts16 + ((size_t)t * NCHUNK + chunk) * NN);
    for (int i = threadIdx.x; i < NN / 2; i += 256) cout[i] = h[i];
}

// ============ CSR 2: totals + in-place exclusive prefix over chunks (packed) ============
__global__ void sumtot16(unsigned short* __restrict__ counts16, int* __restrict__ totals) {
    int idx = blockIdx.x * 256 + threadIdx.x;  // t*(NN/2) + i
    if (idx >= NT * NN / 2) return;
    int t = idx / (NN / 2), i = idx % (NN / 2);
    unsigned* base = (unsigned*)counts16 + (size_t)t * NCHUNK * (NN / 2) + i;
    unsigned run0 = 0, run1 = 0;
#pragma unroll
    for (int c = 0; c < NCHUNK; c++) {
        unsigned v = base[(size_t)c * (NN / 2)];
        base[(size_t)c * (NN / 2)] = run0 | (run1 << 16);
        run0 += v & 0xffffu;
        run1 += v >> 16;
    }
    totals[t * NN + 2 * i]     = (int)run0;
    totals[t * NN + 2 * i + 1] = (int)run1;
}

// ============ CSR 3: exclusive scan per type (1024 threads) ============
__global__ void scan_kernel(const int* __restrict__ totals, int* __restrict__ row_ptr) {
    int t = blockIdx.x, tid = threadIdx.x;
    __shared__ int buf[1024];
    int running = 0;
    for (int base = 0; base < NN; base += 1024) {
        int i = base + tid;
        int v = (i < NN) ? totals[t * NN + i] : 0;
        buf[tid] = v;
        __syncthreads();
        for (int off = 1; off < 1024; off <<= 1) {
            int x = (tid >= off) ? buf[tid - off] : 0;
            __syncthreads();
            buf[tid] += x;
            __syncthreads();
        }
        if (i < NN) row_ptr[t * (NN + 1) + i] = running + buf[tid] - v;
        int tot = buf[1023];
        __syncthreads();
        running += tot;
    }
    if (tid == 0) row_ptr[t * (NN + 1) + NN] = running;
}

// ============ CSR 4: placement; type->XCD affinity so CSR region stays in one L2 ============
__global__ void place2(const int* __restrict__ edges, const unsigned short* __restrict__ counts16,
                       const int* __restrict__ row_ptr, int* __restrict__ csr_src) {
    int t = blockIdx.x & 15, chunk = blockIdx.x >> 4;
    __shared__ unsigned cur[NN / 2];
    for (int i = threadIdx.x; i < NN / 2; i += 256) cur[i] = 0;
    __syncthreads();
    const int* srcp = edges + (size_t)t * 2 * NE + chunk * CHSZ;
    const int* dstp = srcp + NE;
    const unsigned short* cb = counts16 + ((size_t)t * NCHUNK + chunk) * NN;
    const int* rp = row_ptr + t * (NN + 1);
    int* cs = csr_src + (size_t)t * NE;
    for (int e = threadIdx.x; e < CHSZ; e += 256) {
        int d = dstp[e];
        unsigned old = atomicAdd(&cur[d >> 1], (d & 1) ? 0x10000u : 1u);
        int off = (d & 1) ? (int)(old >> 16) : (int)(old & 0xffffu);
        cs[rp[d] + (int)cb[d] + off] = srcp[e];
    }
}

// ============ precompute u = reduce(W * a) over c ============
__global__ void precompute_u(const float* __restrict__ W1, const float* __restrict__ as1,
                             const float* __restrict__ ad1, const float* __restrict__ W2,
                             const float* __restrict__ as2, const float* __restrict__ ad2,
                             float* __restrict__ u1s, float* __restrict__ u1d,
                             float* __restrict__ u2s, float* __restrict__ u2d) {
    int t = blockIdx.x, tid = threadIdx.x;  // 128 threads
    int k = tid >> 2, h = tid & 3;
    float ss = 0.f, dd = 0.f;
    for (int c = 0; c < 32; c++) {
        float w = W2[(size_t)t * 4096 + k * 128 + h * 32 + c];
        ss += w * as2[t * 128 + h * 32 + c];
        dd += w * ad2[t * 128 + h * 32 + c];
    }
    u2s[(t * 32 + k) * 4 + h] = ss;
    u2d[(t * 32 + k) * 4 + h] = dd;
    if (tid < 4) {
        int hh = tid;
        float s1 = 0.f, d1 = 0.f;
        for (int c = 0; c < 32; c++) {
            float w = W1[t * 128 + hh * 32 + c];
            s1 += w * as1[t * 128 + hh * 32 + c];
            d1 += w * ad1[t * 128 + hh * 32 + c];
        }
        u1s[t * 4 + hh] = s1;
        u1d[t * 4 + hh] = d1;
    }
}

// ============ Layer 1: fused attention + aggregation (no max-sub: |logit| < ~1) ============
__global__ void layer1_fused(const float* __restrict__ x, const int* __restrict__ csr_src,
                             const int* __restrict__ row_ptr, const float* __restrict__ u1s,
                             const float* __restrict__ u1d, float4* __restrict__ g1) {
    int t = blockIdx.y;
    int d = blockIdx.x * 256 + threadIdx.x;
    if (d >= NN) return;
    int sc = d_src_of(t), dc = d_dst_of(t);
    float xd = x[dc * NN + d];
    float4 usv = ((const float4*)u1s)[t];
    float4 udv = ((const float4*)u1d)[t];
    float us[4] = {usv.x, usv.y, usv.z, usv.w};
    float dl[4] = {xd * udv.x, xd * udv.y, xd * udv.z, xd * udv.w};
    int rb = row_ptr[t * (NN + 1) + d], re = row_ptr[t * (NN + 1) + d + 1];
    float dn[4] = {0, 0, 0, 0}, a[4] = {0, 0, 0, 0};
    const int* cs = csr_src + (size_t)t * NE;
#pragma unroll 2
    for (int i = rb; i < re; i++) {
        int s = cs[i];
        float xs = x[sc * NN + s];
#pragma unroll
        for (int h = 0; h < 4; h++) {
            float l = xs * us[h] + dl[h];
            l = l > 0.f ? l : NEG * l;
            float p = __expf(l);
            dn[h] += p;
            a[h] += p * xs;
        }
    }
    float4 g;
    g.x = (re > rb) ? a[0] / dn[0] : 0.f;
    g.y = (re > rb) ? a[1] / dn[1] : 0.f;
    g.z = (re > rb) ? a[2] / dn[2] : 0.f;
    g.w = (re > rb) ? a[3] / dn[3] : 0.f;
    g1[t * NN + d] = g;
}

// ============ Layer 1 transform ============
__global__ void transform1(const float4* __restrict__ g1, const float* __restrict__ W1,
                           const float* __restrict__ b1, float* __restrict__ x1) {
    int idx = blockIdx.x * 256 + threadIdx.x;  // [ch][n][c]
    if (idx >= 4 * NN * 32) return;
    int c = idx & 31;
    int n = (idx >> 5) % NN;
    int ch = idx / (NN * 32);
    float sum = 0.f, bs = 0.f;
#pragma unroll
    for (int t = 0; t < NT; t++) {
        if (d_dst_of(t) == ch) {
            float4 g = g1[t * NN + n];
            const float* w = W1 + t * 128 + c;
            sum += 0.25f * (g.x * w[0] + g.y * w[32] + g.z * w[64] + g.w * w[96]);
            bs += b1[t * 32 + c];
        }
    }
    float v = 0.25f * (sum + bs);
    x1[idx] = v > 0.f ? v : 0.f;
}

// ============ Layer 2 scores (float4 k-loop) ============
__global__ void scores2(const float* __restrict__ x1, const float* __restrict__ u2s,
                        const float* __restrict__ u2d, float4* __restrict__ ss,
                        float4* __restrict__ ds) {
    int t = blockIdx.y;
    int n = blockIdx.x * 256 + threadIdx.x;
    if (n >= NN) return;
    int sc = d_src_of(t), dc = d_dst_of(t);
    const float4* xsr = (const float4*)(x1 + ((size_t)sc * NN + n) * 32);
    const float4* xdr = (const float4*)(x1 + ((size_t)dc * NN + n) * 32);
    const float4* us = (const float4*)(u2s + (size_t)t * 128);  // row k = float4 over h
    const float4* ud = (const float4*)(u2d + (size_t)t * 128);
    float4 s4 = make_float4(0.f, 0.f, 0.f, 0.f);
    float4 d4 = make_float4(0.f, 0.f, 0.f, 0.f);
#pragma unroll
    for (int kq = 0; kq < 8; kq++) {
        float4 xs = xsr[kq], xd = xdr[kq];
#pragma unroll
        for (int m = 0; m < 4; m++) {
            float xsk = (&xs.x)[m], xdk = (&xd.x)[m];
            float4 u = us[4 * kq + m], v = ud[4 * kq + m];
            s4.x += xsk * u.x; s4.y += xsk * u.y; s4.z += xsk * u.z; s4.w += xsk * u.w;
            d4.x += xdk * v.x; d4.y += xdk * v.y; d4.z += xdk * v.z; d4.w += xdk * v.w;
        }
    }
    ss[t * NN + n] = s4;
    ds[t * NN + n] = d4;
}

// ============ Layer 2: FULLY-FUSED, lane-parallel softmax + k-parallel aggregation ======
// 32-edge tiles: phase 1 = lane-per-edge exp (4 exp issues per 32 edges, not per edge —
// round-11 lesson: group-redundant exp saturated VALU at 103%), staged to per-group LDS
// (wave-coherent, no barrier); phase 2 = broadcast LDS reads + coalesced x1 gather + FMA.
// dn accumulated as per-lane partials in phase 1, shfl_xor-reduced after the loop.
// No nt loads (r8/r9), no transposed staging (r9), phase loop not unrolled (r4 spill).
__global__ __launch_bounds__(256) void layer2_full(
    const float* __restrict__ x1, const int* __restrict__ csr_src,
    const int* __restrict__ row_ptr, const float4* __restrict__ ss,
    const float4* __restrict__ ds, const float* __restrict__ W2,
    const float* __restrict__ b2, float* __restrict__ out) {
    int b = blockIdx.x;
    int xcd = b & 7;
    int ch = xcd >> 1;
    int dt = (b >> 3) * 2 + (xcd & 1);   // 0..2499, each (ch,dt) exactly once
    int grp = threadIdx.x >> 5, lane = threadIdx.x & 31;
    int d = dt * 8 + grp;
    __shared__ float4 W2s[1024];      // 16 KB
    __shared__ float gl[8 * 128];     // 4 KB
    __shared__ int sStage[8][32];     // 1 KB
    __shared__ float4 pStage[8][32];  // 4 KB -> 25 KB total, 6 blocks/CU
    const float* W2f = (const float*)W2s;
    float o = 0.f, bsum = 0.f;
#pragma unroll 1
    for (int j = 0; j < 4; j++) {
        int t, sc;
        if (j == 0) { t = ch; sc = ch; }
        else {
            int s = (j - 1) + ((j - 1) >= ch ? 1 : 0);        // enumerate s != ch
            t = 4 + s * 3 + (ch > s ? ch - 1 : ch);
            sc = s;
        }
        __syncthreads();  // protect W2s/gl from previous phase readers
        const float4* wsrc = (const float4*)(W2 + (size_t)t * 4096);
#pragma unroll
        for (int i = 0; i < 4; i++) W2s[threadIdx.x + i * 256] = wsrc[threadIdx.x + i * 256];
        bsum += b2[t * 32 + lane];
        float4 dsv = ds[t * NN + d];
        float dl[4] = {dsv.x, dsv.y, dsv.z, dsv.w};
        int rb = row_ptr[t * (NN + 1) + d], re = row_ptr[t * (NN + 1) + d + 1];
        float val[4] = {0, 0, 0, 0};
        float dnl[4] = {0, 0, 0, 0};   // per-lane dn partials
        const int* cs = csr_src + (size_t)t * NE;
        const float4* ssb = ss + (size_t)t * NN;
        const float* xb = x1 + (size_t)sc * NN * 32;
        for (int base = rb; base < re; base += 32) {
            int cnt = re - base; if (cnt > 32) cnt = 32;
            // ---- phase 1: lane-per-edge softmax numerators ----
            int myi = base + lane;
            int sIdx = cs[(myi < re) ? myi : (re - 1)];  // coalesced
            float4 sv = ssb[sIdx];                       // scattered 16B gather
            float p0, p1, p2, p3;
            { float l = sv.x + dl[0]; l = fmaxf(l, NEG * l); p0 = __expf(l); }
            { float l = sv.y + dl[1]; l = fmaxf(l, NEG * l); p1 = __expf(l); }
            { float l = sv.z + dl[2]; l = fmaxf(l, NEG * l); p2 = __expf(l); }
            { float l = sv.w + dl[3]; l = fmaxf(l, NEG * l); p3 = __expf(l); }
            if (lane >= cnt) { p0 = p1 = p2 = p3 = 0.f; }
            dnl[0] += p0; dnl[1] += p1; dnl[2] += p2; dnl[3] += p3;
            sStage[grp][lane] = sIdx;
            pStage[grp][lane] = make_float4(p0, p1, p2, p3);
            // same wave writes then reads its own region: in-order, no barrier
            // ---- phase 2: k-parallel aggregation ----
#pragma unroll 4
            for (int u = 0; u < cnt; u++) {
                int s = sStage[grp][u];          // LDS broadcast
                float4 p4 = pStage[grp][u];      // LDS broadcast b128
                float xk = xb[s * 32 + lane];    // coalesced 128B per group
                val[0] += p4.x * xk;
                val[1] += p4.y * xk;
                val[2] += p4.z * xk;
                val[3] += p4.w * xk;
            }
        }
        // reduce dn partials across the 32-lane group (offsets <32 stay in-half)
#pragma unroll
        for (int off = 1; off <= 16; off <<= 1) {
#pragma unroll
            for (int h = 0; h < 4; h++) dnl[h] += __shfl_xor(dnl[h], off);
        }
        float r0 = (re > rb) ? 1.f / dnl[0] : 0.f;
        float r1 = (re > rb) ? 1.f / dnl[1] : 0.f;
        float r2 = (re > rb) ? 1.f / dnl[2] : 0.f;
        float r3 = (re > rb) ? 1.f / dnl[3] : 0.f;
        gl[grp * 128 +       lane] = val[0] * r0;
        gl[grp * 128 +  32 + lane] = val[1] * r1;
        gl[grp * 128 +  64 + lane] = val[2] * r2;
        gl[grp * 128 +  96 + lane] = val[3] * r3;
        __syncthreads();
        float acc = 0.f;
#pragma unroll 4
        for (int k = 0; k < 32; k++) {
            const float* gb = gl + grp * 128 + k;
            const float* wb = W2f + k * 128 + lane;
            acc += gb[0] * wb[0] + gb[32] * wb[32] + gb[64] * wb[64] + gb[96] * wb[96];
        }
        o += acc;
    }
    float r = o * 0.0625f + bsum * 0.25f;  // (/H=4 then /4 types) ; (bias sum)/4
    r = r > 0.f ? r : 0.f;
    out[(size_t)d * 128 + ch * 32 + lane] = r;
}

extern "C" void kernel_launch(void* const* d_in, const int* in_sizes, int n_in,
                              void* d_out, int out_size, void* d_ws, size_t ws_size,
                              hipStream_t stream) {
    const float* x   = (const float*)d_in[0];
    const int*   edg = (const int*)d_in[1];
    const float* W1  = (const float*)d_in[2];
    const float* as1 = (const float*)d_in[3];
    const float* ad1 = (const float*)d_in[4];
    const float* b1  = (const float*)d_in[5];
    const float* W2  = (const float*)d_in[6];
    const float* as2 = (const float*)d_in[7];
    const float* ad2 = (const float*)d_in[8];
    const float* b2  = (const float*)d_in[9];
    float* out = (float*)d_out;

    char* w = (char*)d_ws;
    auto carve = [&](size_t bytes) {
        void* p = (void*)w;
        w += (bytes + 255) & ~(size_t)255;
        return p;
    };
    int*   csr_src = (int*)carve((size_t)NT * NE * 4);        // 20.5 MB
    int*   row_ptr = (int*)carve((size_t)NT * (NN + 1) * 4);  // 1.3 MB
    float* u1s     = (float*)carve(NT * 4 * 4);
    float* u1d     = (float*)carve(NT * 4 * 4);
    float* u2s     = (float*)carve(NT * 32 * 4 * 4);
    float* u2d     = (float*)carve(NT * 32 * 4 * 4);
    float* x1      = (float*)carve((size_t)4 * NN * 32 * 4);  // 10.2 MB
    float* ss      = (float*)carve((size_t)NT * NN * 4 * 4);  // 5.1 MB
    float* ds      = (float*)carve((size_t)NT * NN * 4 * 4);  // 5.1 MB
    // time-multiplexed region: {counts16 10.2MB + totals 1.3MB} -> {g1 5.1MB}
    char* region   = (char*)carve((size_t)NT * NCHUNK * NN * 2 + (size_t)NT * NN * 4 + 512);
    unsigned short* counts16 = (unsigned short*)region;
    int*            totals   = (int*)(region + (size_t)NT * NCHUNK * NN * 2);
    float4*         g1       = (float4*)region;

    // ---- CSR build ----
    hist2<<<NT * NCHUNK, 256, 0, stream>>>(edg, counts16);
    sumtot16<<<(NT * NN / 2 + 255) / 256, 256, 0, stream>>>(counts16, totals);
    scan_kernel<<<NT, 1024, 0, stream>>>(totals, row_ptr);
    place2<<<NT * NCHUNK, 256, 0, stream>>>(edg, counts16, row_ptr, csr_src);
    precompute_u<<<NT, 128, 0, stream>>>(W1, as1, ad1, W2, as2, ad2, u1s, u1d, u2s, u2d);

    // ---- Layer 1 ----
    dim3 gtn((NN + 255) / 256, NT);
    layer1_fused<<<gtn, 256, 0, stream>>>(x, csr_src, row_ptr, u1s, u1d, g1);
    transform1<<<(4 * NN * 32 + 255) / 256, 256, 0, stream>>>(g1, W1, b1, x1);

    // ---- Layer 2 ----
    scores2<<<gtn, 256, 0, stream>>>(x1, u2s, u2d, (float4*)ss, (float4*)ds);
    layer2_full<<<10000, 256, 0, stream>>>(x1, csr_src, row_ptr, (const float4*)ss,
                                           (const float4*)ds, W2, b2, out);
}